// Round 9
// baseline (283.813 us; speedup 1.0000x reference)
//
#include <hip/hip_runtime.h>

// ---------------------------------------------------------------------------
// SelfMultiHeadAttn: x[B,S,H] -> LN(x + OutProj(SDPA(RoPE(q), RoPE(k/|k|), v)))
// B=2 S=2048 H=1024 R=16 heads, K=64 head dim. fp32 in/out.
// Ledger: R12 224.7 | R13 ✗ | R14 ✗ | R15 223.2 | R16 221.2 WIN | R17 212.9
//         WIN | R18 209.8 WIN (attn 8-wave KVBLK=256: 45.1us, MfmaUtil 30.7,
//         VALU 37.9 -> ~31% stall; MFMA floor ~17us, 2 waves/SIMD).
// R19 = R18 + (a) T5 s_setprio(1) around attn QK/PV MFMA clusters (m191:
//       +4-7% attn with phase drift; isolated this time, unlike R13 bundle);
//       (b) ps tree-sum: serial 16-deep f32 add chain -> depth-5 pairwise
//       tree (positive values; error neutral-or-better).
// ---------------------------------------------------------------------------

#define B_   2
#define S_   2048
#define H_   1024
#define R_   16
#define BS_  (B_*S_)     // 4096 rows
#define NQKV 3072        // R*K*3
#define LOG2E 1.44269504088896f

typedef float    floatx4 __attribute__((ext_vector_type(4)));
typedef _Float16 half8   __attribute__((ext_vector_type(8)));
typedef _Float16 half4   __attribute__((ext_vector_type(4)));
typedef __fp16   fp16x2  __attribute__((ext_vector_type(2)));  // cvt_pkrtz ret

#if __has_builtin(__builtin_amdgcn_exp2f)
#define EXP2(x) __builtin_amdgcn_exp2f(x)
#else
#define EXP2(x) exp2f(x)
#endif

// async global -> LDS, 16 B per lane (lds dest = wave-uniform base + lane*16)
__device__ __forceinline__ void gl_lds16(const _Float16* g, _Float16* l) {
    __builtin_amdgcn_global_load_lds(
        (const __attribute__((address_space(1))) unsigned int*)g,
        (__attribute__((address_space(3))) unsigned int*)l, 16, 0, 0);
}

// ------- fused preprocessing: x cast + W_qkv^T + W_out^T (one launch) ------
// grid 8192: [0,4096) cast x; [4096,7168) W_qkv transpose; [7168,8192) W_out.
__global__ __launch_bounds__(256) void prep0_kernel(
    const float* __restrict__ x, _Float16* __restrict__ x_h,
    const float* __restrict__ W_qkv, _Float16* __restrict__ wqkv_t,
    const float* __restrict__ W_out, _Float16* __restrict__ wout_t)
{
    __shared__ float tile[32][33];
    int bid = blockIdx.x, tid = threadIdx.x;
    if (bid < 4096) {
        int i = bid * 1024 + tid * 4;
        float4 v = *(const float4*)(x + i);
        half4 h;
        h.x = (_Float16)v.x; h.y = (_Float16)v.y;
        h.z = (_Float16)v.z; h.w = (_Float16)v.w;
        *(half4*)(x_h + i) = h;
        return;
    }
    const float* in; _Float16* out; int rows, cols, bx, by;
    if (bid < 7168) {
        int t = bid - 4096;
        in = W_qkv; out = wqkv_t; rows = H_; cols = NQKV;
        bx = t % 96; by = t / 96;
    } else {
        int t = bid - 7168;
        in = W_out; out = wout_t; rows = H_; cols = H_;
        bx = t & 31; by = t >> 5;
    }
    int cx = bx * 32, ry = by * 32;
    int tx = tid & 31, ty = tid >> 5;   // ty 0..7
#pragma unroll
    for (int i = 0; i < 32; i += 8)
        tile[ty + i][tx] = in[(size_t)(ry + ty + i) * cols + cx + tx];
    __syncthreads();
#pragma unroll
    for (int i = 0; i < 32; i += 8)
        out[(size_t)(cx + ty + i) * rows + ry + tx] = (_Float16)tile[tx][ty + i];
}

// ---------- f16 MFMA GEMM 128x128, dbuf:  Ch(f16) = A @ Bt^T + bias --------
__global__ __launch_bounds__(256) void gemm_f16_mfma(
    const _Float16* __restrict__ A, const _Float16* __restrict__ Bt,
    const float* __restrict__ bias, _Float16* __restrict__ Ch,
    int M, int N, int Kd)
{
    __shared__ _Float16 Als[2][4096];
    __shared__ _Float16 Bls[2][4096];
    int tid  = threadIdx.x;
    int lane = tid & 63, w = tid >> 6;
    int wr = w >> 1, wc = w & 1;
    int fr = lane & 15, fq = lane >> 4;

    int nbx = gridDim.x;
    int orig = blockIdx.x + nbx * blockIdx.y;
    int nwg  = nbx * gridDim.y;
    int swz  = (nwg & 7) ? orig : ((orig & 7) * (nwg >> 3) + (orig >> 3));
    int bx = swz % nbx, by = swz / nbx;
    int m0 = by * 128, n0 = bx * 128;

    floatx4 acc[4][4] = {};

    const _Float16* ga[2]; const _Float16* gb[2];
    int loff[2];
#pragma unroll
    for (int i2 = 0; i2 < 2; ++i2) {
        int ch = 2 * w + i2;
        int row = ch * 16 + (lane >> 2), col = (lane & 3) * 8;
        ga[i2] = A  + (size_t)(m0 + row) * Kd + col;
        gb[i2] = Bt + (size_t)(n0 + row) * Kd + col;
        loff[i2] = ch * 512;
    }

    int nIter = Kd >> 5;
#pragma unroll
    for (int i2 = 0; i2 < 2; ++i2) {
        gl_lds16(ga[i2], &Als[0][loff[i2]]);
        gl_lds16(gb[i2], &Bls[0][loff[i2]]);
    }

    for (int it = 0; it < nIter; ++it) {
        int cur = it & 1;
        __syncthreads();               // buf[cur] staged; buf[cur^1] free
        if (it + 1 < nIter) {
            int k1 = (it + 1) << 5;
#pragma unroll
            for (int i2 = 0; i2 < 2; ++i2) {
                gl_lds16(ga[i2] + k1, &Als[cur ^ 1][loff[i2]]);
                gl_lds16(gb[i2] + k1, &Bls[cur ^ 1][loff[i2]]);
            }
        }
        const _Float16* Ab = Als[cur];
        const _Float16* Bb = Bls[cur];
        half8 af[4], bf[4];
#pragma unroll
        for (int i = 0; i < 4; ++i)
            af[i] = *(const half8*)(Ab + (wr * 64 + i * 16 + fr) * 32 + fq * 8);
#pragma unroll
        for (int j = 0; j < 4; ++j)
            bf[j] = *(const half8*)(Bb + (wc * 64 + j * 16 + fr) * 32 + fq * 8);
#pragma unroll
        for (int i = 0; i < 4; ++i)
#pragma unroll
            for (int j = 0; j < 4; ++j)
                acc[i][j] = __builtin_amdgcn_mfma_f32_16x16x32_f16(
                    af[i], bf[j], acc[i][j], 0, 0, 0);
    }

#pragma unroll
    for (int i = 0; i < 4; ++i)
#pragma unroll
        for (int j = 0; j < 4; ++j)
#pragma unroll
            for (int r2 = 0; r2 < 4; ++r2) {
                int row = m0 + wr * 64 + i * 16 + fq * 4 + r2;
                int col = n0 + wc * 64 + j * 16 + fr;
                Ch[(size_t)row * N + col] = (_Float16)(acc[i][j][r2] + bias[col]);
            }
}

// ---------- f16 MFMA GEMM 64x64, dbuf: Cf(f32) = A@Bt^T + bias + resid -----
// 4 waves, each 32x32 (2x2 frags). grid (N/64, M/64) -> 4 blocks/CU.
__global__ __launch_bounds__(256) void gemm64_f16_mfma(
    const _Float16* __restrict__ A, const _Float16* __restrict__ Bt,
    const float* __restrict__ bias, const float* __restrict__ resid,
    float* __restrict__ Cf, int M, int N, int Kd)
{
    __shared__ _Float16 Als[2][2048];
    __shared__ _Float16 Bls[2][2048];
    int tid = threadIdx.x, lane = tid & 63, w = tid >> 6;
    int wr = w >> 1, wc = w & 1;
    int fr = lane & 15, fq = lane >> 4;

    int nbx = gridDim.x;
    int orig = blockIdx.x + nbx * blockIdx.y;
    int nwg  = nbx * gridDim.y;
    int swz  = (nwg & 7) ? orig : ((orig & 7) * (nwg >> 3) + (orig >> 3));
    int bx = swz % nbx, by = swz / nbx;
    int m0 = by * 64, n0 = bx * 64;

    floatx4 acc[2][2] = {};

    int srow = w * 16 + (lane >> 2), scol = (lane & 3) * 8;
    const _Float16* ga = A  + (size_t)(m0 + srow) * Kd + scol;
    const _Float16* gb = Bt + (size_t)(n0 + srow) * Kd + scol;
    int loff = w * 512;

    int nIter = Kd >> 5;
    gl_lds16(ga, &Als[0][loff]);
    gl_lds16(gb, &Bls[0][loff]);

    for (int it = 0; it < nIter; ++it) {
        int cur = it & 1;
        __syncthreads();
        if (it + 1 < nIter) {
            int k1 = (it + 1) << 5;
            gl_lds16(ga + k1, &Als[cur ^ 1][loff]);
            gl_lds16(gb + k1, &Bls[cur ^ 1][loff]);
        }
        const _Float16* Ab = Als[cur];
        const _Float16* Bb = Bls[cur];
        half8 af[2], bf[2];
#pragma unroll
        for (int i = 0; i < 2; ++i)
            af[i] = *(const half8*)(Ab + (wr * 32 + i * 16 + fr) * 32 + fq * 8);
#pragma unroll
        for (int j = 0; j < 2; ++j)
            bf[j] = *(const half8*)(Bb + (wc * 32 + j * 16 + fr) * 32 + fq * 8);
#pragma unroll
        for (int i = 0; i < 2; ++i)
#pragma unroll
            for (int j = 0; j < 2; ++j)
                acc[i][j] = __builtin_amdgcn_mfma_f32_16x16x32_f16(
                    af[i], bf[j], acc[i][j], 0, 0, 0);
    }

#pragma unroll
    for (int i = 0; i < 2; ++i)
#pragma unroll
        for (int j = 0; j < 2; ++j)
#pragma unroll
            for (int r2 = 0; r2 < 4; ++r2) {
                int row = m0 + wr * 32 + i * 16 + fq * 4 + r2;
                int col = n0 + wc * 32 + j * 16 + fr;
                Cf[(size_t)row * N + col] =
                    acc[i][j][r2] + bias[col] + resid[(size_t)row * N + col];
            }
}

// ------- fused prep1: k-norm + RoPE -> qt/kt f16; V -> vt2 image -----------
__global__ __launch_bounds__(256) void prep1_kernel(
    const _Float16* __restrict__ qkvh, const float* __restrict__ pos,
    _Float16* __restrict__ qt, _Float16* __restrict__ kt,
    _Float16* __restrict__ vt2)
{
    __shared__ float tile[64][65];
    int head = blockIdx.x, tau = blockIdx.y;
    int s0 = tau * 64;
    int b = head >> 4, rh = head & 15;
    int lane = threadIdx.x & 63, w = threadIdx.x >> 6;

#pragma unroll
    for (int si = w; si < 64; si += 4)
        tile[si][lane] =
            (float)qkvh[(size_t)(b * S_ + s0 + si) * NQKV + rh * 192 + 128 + lane];
    __syncthreads();
    {
        int P = lane;
        int op = P >> 3;
        int hi = (P >> 2) & 1, lo = P & 3;
#pragma unroll
        for (int d = w; d < 64; d += 4) {
            int ol = op ^ (d & 7);
            int key = 32 * (ol >> 2) + 16 * hi + 4 * (ol & 3) + lo;
            vt2[(((size_t)head * 32 + tau) * 64 + d) * 64 + P] = (_Float16)tile[key][d];
        }
    }

    for (int i = 0; i < 16; ++i) {
        int s = s0 + w * 16 + i;
        int bs = b * S_ + s;
        const _Float16* base = qkvh + (size_t)bs * NQKV + rh * 192;
        float qv = (float)base[lane];
        float kv = (float)base[64 + lane];

        float ss = kv * kv;
#pragma unroll
        for (int off = 32; off > 0; off >>= 1) ss += __shfl_xor(ss, off);
        kv *= rsqrtf(ss);

        int j = lane & 31;
        float sn = pos[(size_t)bs * 64 + j];
        float cs = pos[(size_t)bs * 64 + 32 + j];
        float qp = __shfl_xor(qv, 32);
        float kp = __shfl_xor(kv, 32);
        float qo, ko;
        if (lane < 32) { qo = qv * cs - qp * sn; ko = kv * cs - kp * sn; }
        else           { qo = qp * sn + qv * cs; ko = kp * sn + kv * cs; }

        size_t oidx = ((size_t)head * S_ + s) * 64 + lane;
        qt[oidx] = (_Float16)(qo * LOG2E);   // fold log2(e) into q~
        kt[oidx] = (_Float16)ko;
    }
}

// ------- transposed MFMA flash attention, 8-wave blocks, KVBLK=256 ---------
// grid (8 q-tiles of 256, 32 heads) [qtile-fastest], block 512 = 8 waves;
// wave w owns 32 queries (2 q-groups of 16) at q0 + w*32. 8 intervals x 256
// keys (4 sub-tiles of 64) cover all 2048 keys. K/V double-buffered in LDS
// (128 KB); 8 waves share the tile. Static-max softmax; normalization in
// epilogue; writes ctx directly. setprio(1) wraps MFMA clusters (T5);
// ps summed as depth-5 pairwise tree (was serial 16-chain).
// XCD swizzle: chunk of 32 blocks = 4 heads x 8 qtiles -> 2 MB K/V per L2.
__global__ __launch_bounds__(512) void attn_mfma_kernel(
    const _Float16* __restrict__ qt, const _Float16* __restrict__ kt,
    const _Float16* __restrict__ vt2, _Float16* __restrict__ ctx)
{
    __shared__ _Float16 Kls[2][16384];
    __shared__ _Float16 Vls[2][16384];

    int orig = blockIdx.x + 8 * blockIdx.y;        // 256 blocks
    int swz  = (orig & 7) * 32 + (orig >> 3);
    int q0   = (swz & 7) * 256;
    int head = swz >> 3;

    int b = head >> 4, rh = head & 15;
    int tid = threadIdx.x, lane = tid & 63, w = tid >> 6;   // w in [0,8)
    int g = lane >> 4, c = lane & 15;

    // Q B-frags + static softmax bound mL = |q~| (log2 units) per q-group
    half8 qf[2][2];
    floatx4 mz[2];                  // broadcast(-mL) for MFMA C-init
    float l_s[2] = {0.f, 0.f};
#pragma unroll
    for (int qg = 0; qg < 2; ++qg) {
        const _Float16* qp =
            qt + ((size_t)head * S_ + q0 + w * 32 + qg * 16 + c) * 64 + 8 * g;
        qf[qg][0] = *(const half8*)qp;
        qf[qg][1] = *(const half8*)(qp + 32);
        float qq = 0.f;
#pragma unroll
        for (int i = 0; i < 8; ++i) {
            float a = (float)qf[qg][0][i], b2 = (float)qf[qg][1][i];
            qq += a * a + b2 * b2;
        }
        qq += __shfl_xor(qq, 16);
        qq += __shfl_xor(qq, 32);
        float nm = -sqrtf(qq);    // s_log2 <= |q~|*|k^| (k^ unit norm)
        mz[qg][0] = nm; mz[qg][1] = nm; mz[qg][2] = nm; mz[qg][3] = nm;
    }

    floatx4 o_acc[2][4] = {};

    // staging geometry: wave w stages K chunk w and V chunk w of each
    // sub-tile (chunk = 8 keys x 64 d = 512 f16, staged 16B/lane).
    int krow = w * 8 + (lane >> 3);
    int koct = (lane & 7) ^ (lane >> 3);
    const _Float16* kg = kt + ((size_t)head * S_ + krow) * 64 + koct * 8;
    const _Float16* vg = vt2 + ((size_t)head * 32) * 4096 + w * 512 + lane * 8;
    int loff = w * 512;

    int co = c & 7;        // XOR swizzle term for frag reads

    // prologue: stage sub-tiles 0..3 into buffer 0
#pragma unroll
    for (int s = 0; s < 4; ++s) {
        gl_lds16(kg + (size_t)s * 4096, &Kls[0][s * 4096 + loff]);
        gl_lds16(vg + (size_t)s * 4096, &Vls[0][s * 4096 + loff]);
    }

    for (int jt = 0; jt < 8; ++jt) {
        int cur = jt & 1;
        __syncthreads();       // buf[cur] staged (4 sub-tiles); buf[cur^1] free
        if (jt + 1 < 8) {
#pragma unroll
            for (int s = 0; s < 4; ++s) {
                size_t joff = (size_t)(4 * (jt + 1) + s) * 4096;
                gl_lds16(kg + joff, &Kls[cur ^ 1][s * 4096 + loff]);
                gl_lds16(vg + joff, &Vls[cur ^ 1][s * 4096 + loff]);
            }
        }

#pragma unroll
        for (int s = 0; s < 4; ++s) {
            const _Float16* Kbuf = &Kls[cur][s * 4096];
            const _Float16* Vbuf = &Vls[cur][s * 4096];

            // ---- K fragments once, shared by both q-groups ----
            half8 kfr[8];
#pragma unroll
            for (int t = 0; t < 4; ++t) {
                const _Float16* krw = Kbuf + (16 * t + c) * 64;
                kfr[2 * t]     = *(const half8*)(krw + ((g) ^ co) * 8);
                kfr[2 * t + 1] = *(const half8*)(krw + ((4 + g) ^ co) * 8);
            }

            union { half8 v; fp16x2 h2[4]; } pf[2][2];
#pragma unroll
            for (int qg = 0; qg < 2; ++qg) {
                floatx4 sacc[4];
                __builtin_amdgcn_s_setprio(1);
#pragma unroll
                for (int t = 0; t < 4; ++t) {
                    floatx4 z = mz[qg];   // C-init = -mL : sacc = S - mL
                    z = __builtin_amdgcn_mfma_f32_16x16x32_f16(
                        kfr[2 * t], qf[qg][0], z, 0, 0, 0);
                    z = __builtin_amdgcn_mfma_f32_16x16x32_f16(
                        kfr[2 * t + 1], qf[qg][1], z, 0, 0, 0);
                    sacc[t] = z;
                }
                __builtin_amdgcn_s_setprio(0);
#pragma unroll
                for (int t = 0; t < 4; ++t)
#pragma unroll
                    for (int r = 0; r < 4; ++r)
                        sacc[t][r] = EXP2(sacc[t][r]);
                // pairwise tree sum (depth 5 vs serial 16)
                float t0 = (sacc[0][0] + sacc[0][1]) + (sacc[0][2] + sacc[0][3]);
                float t1 = (sacc[1][0] + sacc[1][1]) + (sacc[1][2] + sacc[1][3]);
                float t2 = (sacc[2][0] + sacc[2][1]) + (sacc[2][2] + sacc[2][3]);
                float t3 = (sacc[3][0] + sacc[3][1]) + (sacc[3][2] + sacc[3][3]);
                l_s[qg] += (t0 + t1) + (t2 + t3);
                pf[qg][0].h2[0] = __builtin_amdgcn_cvt_pkrtz(sacc[0][0], sacc[0][1]);
                pf[qg][0].h2[1] = __builtin_amdgcn_cvt_pkrtz(sacc[0][2], sacc[0][3]);
                pf[qg][0].h2[2] = __builtin_amdgcn_cvt_pkrtz(sacc[1][0], sacc[1][1]);
                pf[qg][0].h2[3] = __builtin_amdgcn_cvt_pkrtz(sacc[1][2], sacc[1][3]);
                pf[qg][1].h2[0] = __builtin_amdgcn_cvt_pkrtz(sacc[2][0], sacc[2][1]);
                pf[qg][1].h2[1] = __builtin_amdgcn_cvt_pkrtz(sacc[2][2], sacc[2][3]);
                pf[qg][1].h2[2] = __builtin_amdgcn_cvt_pkrtz(sacc[3][0], sacc[3][1]);
                pf[qg][1].h2[3] = __builtin_amdgcn_cvt_pkrtz(sacc[3][2], sacc[3][3]);
            }

            // ---- V fragments once, shared; O^T += V^T @ P^T ----
            __builtin_amdgcn_s_setprio(1);
#pragma unroll
            for (int t = 0; t < 4; ++t) {
                const _Float16* vrow = Vbuf + (16 * t + c) * 64;
                half8 v0 = *(const half8*)(vrow + ((g) ^ co) * 8);
                half8 v1 = *(const half8*)(vrow + ((4 + g) ^ co) * 8);
#pragma unroll
                for (int qg = 0; qg < 2; ++qg) {
                    o_acc[qg][t] = __builtin_amdgcn_mfma_f32_16x16x32_f16(
                        v0, pf[qg][0].v, o_acc[qg][t], 0, 0, 0);
                    o_acc[qg][t] = __builtin_amdgcn_mfma_f32_16x16x32_f16(
                        v1, pf[qg][1].v, o_acc[qg][t], 0, 0, 0);
                }
            }
            __builtin_amdgcn_s_setprio(0);
        }
    }

    // ---- epilogue: normalize (f32) and write ctx directly ----
#pragma unroll
    for (int qg = 0; qg < 2; ++qg) {
        float lt = l_s[qg];
        lt += __shfl_xor(lt, 16);
        lt += __shfl_xor(lt, 32);
        float inv = 1.f / lt;
        int q = q0 + w * 32 + qg * 16 + c;
        size_t rowbase = (size_t)(b * S_ + q) * 1024 + rh * 64;
#pragma unroll
        for (int t = 0; t < 4; ++t) {
            union { half4 v; fp16x2 h2[2]; } e;
            e.h2[0] = __builtin_amdgcn_cvt_pkrtz(o_acc[qg][t][0] * inv,
                                                 o_acc[qg][t][1] * inv);
            e.h2[1] = __builtin_amdgcn_cvt_pkrtz(o_acc[qg][t][2] * inv,
                                                 o_acc[qg][t][3] * inv);
            *(half4*)(ctx + rowbase + 16 * t + 4 * g) = e.v;
        }
    }
}

// --------------------- LayerNorm in place on y[4096][1024] -----------------
__global__ __launch_bounds__(256) void ln_kernel(
    float* __restrict__ y, const float* __restrict__ g, const float* __restrict__ bb)
{
    int row = blockIdx.x, tid = threadIdx.x;
    float* p = y + (size_t)row * 1024;
    float4 v = ((const float4*)p)[tid];
    float sum = v.x + v.y + v.z + v.w;
    float sq  = v.x*v.x + v.y*v.y + v.z*v.z + v.w*v.w;
#pragma unroll
    for (int off = 32; off > 0; off >>= 1) {
        sum += __shfl_xor(sum, off);
        sq  += __shfl_xor(sq,  off);
    }
    __shared__ float rs[4], rq[4];
    int w = tid >> 6;
    if ((tid & 63) == 0) { rs[w] = sum; rq[w] = sq; }
    __syncthreads();
    sum = rs[0] + rs[1] + rs[2] + rs[3];
    sq  = rq[0] + rq[1] + rq[2] + rq[3];
    float mean = sum * (1.f / 1024.f);
    float var  = sq * (1.f / 1024.f) - mean * mean;
    float inv  = rsqrtf(var + 1e-5f);
    float4 gv = ((const float4*)g)[tid];
    float4 bv = ((const float4*)bb)[tid];
    v.x = (v.x - mean) * inv * gv.x + bv.x;
    v.y = (v.y - mean) * inv * gv.y + bv.y;
    v.z = (v.z - mean) * inv * gv.z + bv.z;
    v.w = (v.w - mean) * inv * gv.w + bv.w;
    ((float4*)p)[tid] = v;
}

// ---------------------------------------------------------------------------
extern "C" void kernel_launch(void* const* d_in, const int* in_sizes, int n_in,
                              void* d_out, int out_size, void* d_ws, size_t ws_size,
                              hipStream_t stream)
{
    const float* x     = (const float*)d_in[0];
    const float* pos   = (const float*)d_in[1];
    const float* W_qkv = (const float*)d_in[2];
    const float* b_qkv = (const float*)d_in[3];
    const float* W_out = (const float*)d_in[4];
    const float* b_out = (const float*)d_in[5];
    const float* ln_g  = (const float*)d_in[6];
    const float* ln_b  = (const float*)d_in[7];
    float* out = (float*)d_out;

    // workspace layout — 64 MB peak via time-disjoint aliasing:
    //   [ 0, 8)   x_h   (steps 1-2)   then ctx   (steps 4-6, attn writes it)
    //   [ 8,14)   wqkv_t (steps 1-2)
    //   [14,16)   wout_t (steps 1-6)
    //   [16,40)   qkvh  (steps 2-3)
    //   [40,48)   qt    (steps 3-4)
    //   [48,56)   kt    (steps 3-4)
    //   [56,64)   vt2   (steps 3-4)
    char* ws = (char*)d_ws;
    _Float16* x_h    = (_Float16*)(ws);
    _Float16* ctx_h  = (_Float16*)(ws);                       // alias x_h
    _Float16* wqkv_t = (_Float16*)(ws + ((size_t)8  << 20));
    _Float16* wout_t = (_Float16*)(ws + ((size_t)14 << 20));
    _Float16* qkvh   = (_Float16*)(ws + ((size_t)16 << 20));
    _Float16* qt_h   = (_Float16*)(ws + ((size_t)40 << 20));
    _Float16* kt_h   = (_Float16*)(ws + ((size_t)48 << 20));
    _Float16* vt2_h  = (_Float16*)(ws + ((size_t)56 << 20));

    // 1) fused cast + weight transposes
    prep0_kernel<<<8192, 256, 0, stream>>>(x, x_h, W_qkv, wqkv_t, W_out, wout_t);

    // 2) qkv (f16) = x @ W_qkv + b_qkv
    gemm_f16_mfma<<<dim3(NQKV / 128, BS_ / 128), 256, 0, stream>>>(
        x_h, wqkv_t, b_qkv, qkvh, BS_, NQKV, H_);

    // 3) fused k-norm + RoPE + V-image
    prep1_kernel<<<dim3(32, 32), 256, 0, stream>>>(qkvh, pos, qt_h, kt_h, vt2_h);

    // 4) MFMA flash attention (8-wave blocks, KVBLK=256) -> ctx f16
    attn_mfma_kernel<<<dim3(8, 32), 512, 0, stream>>>(
        qt_h, kt_h, vt2_h, ctx_h);

    // 5) out (fp32) = x + ctx @ W_out + b_out   (64x64 tiles, 4 blocks/CU)
    gemm64_f16_mfma<<<dim3(H_ / 64, BS_ / 64), 256, 0, stream>>>(
        ctx_h, wout_t, b_out, x, out, BS_, H_, H_);

    // 6) LayerNorm in place
    ln_kernel<<<BS_, 256, 0, stream>>>(out, ln_g, ln_b);
}

// Round 10
// 206.062 us; speedup vs baseline: 1.3773x; 1.3773x over previous
//
#include <hip/hip_runtime.h>

// ---------------------------------------------------------------------------
// SelfMultiHeadAttn: x[B,S,H] -> LN(x + OutProj(SDPA(RoPE(q), RoPE(k/|k|), v)))
// B=2 S=2048 H=1024 R=16 heads, K=64 head dim. fp32 in/out.
// Ledger: R12 224.7 | R13 ✗ | R14 ✗ | R15 223.2 | R16 221.2 WIN | R17 212.9
//         WIN | R18 209.8 WIN | R19 ✗✗ 283.8 (setprio + tree-sum -> scratch
//         spills: FETCH 13->160 MB, WRITE 10->294 MB, MfmaUtil 30.7->10.5;
//         BANKED: no VALU micro-opts in attn without .s spill check).
// R20 = exact revert to R18 (verified 209.8): attn 8-wave KVBLK=256,
//       serial ps accumulation, no setprio. Re-anchoring before the QKV
//       GEMM pivot next round.
// ---------------------------------------------------------------------------

#define B_   2
#define S_   2048
#define H_   1024
#define R_   16
#define BS_  (B_*S_)     // 4096 rows
#define NQKV 3072        // R*K*3
#define LOG2E 1.44269504088896f

typedef float    floatx4 __attribute__((ext_vector_type(4)));
typedef _Float16 half8   __attribute__((ext_vector_type(8)));
typedef _Float16 half4   __attribute__((ext_vector_type(4)));
typedef __fp16   fp16x2  __attribute__((ext_vector_type(2)));  // cvt_pkrtz ret

#if __has_builtin(__builtin_amdgcn_exp2f)
#define EXP2(x) __builtin_amdgcn_exp2f(x)
#else
#define EXP2(x) exp2f(x)
#endif

// async global -> LDS, 16 B per lane (lds dest = wave-uniform base + lane*16)
__device__ __forceinline__ void gl_lds16(const _Float16* g, _Float16* l) {
    __builtin_amdgcn_global_load_lds(
        (const __attribute__((address_space(1))) unsigned int*)g,
        (__attribute__((address_space(3))) unsigned int*)l, 16, 0, 0);
}

// ------- fused preprocessing: x cast + W_qkv^T + W_out^T (one launch) ------
// grid 8192: [0,4096) cast x; [4096,7168) W_qkv transpose; [7168,8192) W_out.
__global__ __launch_bounds__(256) void prep0_kernel(
    const float* __restrict__ x, _Float16* __restrict__ x_h,
    const float* __restrict__ W_qkv, _Float16* __restrict__ wqkv_t,
    const float* __restrict__ W_out, _Float16* __restrict__ wout_t)
{
    __shared__ float tile[32][33];
    int bid = blockIdx.x, tid = threadIdx.x;
    if (bid < 4096) {
        int i = bid * 1024 + tid * 4;
        float4 v = *(const float4*)(x + i);
        half4 h;
        h.x = (_Float16)v.x; h.y = (_Float16)v.y;
        h.z = (_Float16)v.z; h.w = (_Float16)v.w;
        *(half4*)(x_h + i) = h;
        return;
    }
    const float* in; _Float16* out; int rows, cols, bx, by;
    if (bid < 7168) {
        int t = bid - 4096;
        in = W_qkv; out = wqkv_t; rows = H_; cols = NQKV;
        bx = t % 96; by = t / 96;
    } else {
        int t = bid - 7168;
        in = W_out; out = wout_t; rows = H_; cols = H_;
        bx = t & 31; by = t >> 5;
    }
    int cx = bx * 32, ry = by * 32;
    int tx = tid & 31, ty = tid >> 5;   // ty 0..7
#pragma unroll
    for (int i = 0; i < 32; i += 8)
        tile[ty + i][tx] = in[(size_t)(ry + ty + i) * cols + cx + tx];
    __syncthreads();
#pragma unroll
    for (int i = 0; i < 32; i += 8)
        out[(size_t)(cx + ty + i) * rows + ry + tx] = (_Float16)tile[tx][ty + i];
}

// ---------- f16 MFMA GEMM 128x128, dbuf:  Ch(f16) = A @ Bt^T + bias --------
__global__ __launch_bounds__(256) void gemm_f16_mfma(
    const _Float16* __restrict__ A, const _Float16* __restrict__ Bt,
    const float* __restrict__ bias, _Float16* __restrict__ Ch,
    int M, int N, int Kd)
{
    __shared__ _Float16 Als[2][4096];
    __shared__ _Float16 Bls[2][4096];
    int tid  = threadIdx.x;
    int lane = tid & 63, w = tid >> 6;
    int wr = w >> 1, wc = w & 1;
    int fr = lane & 15, fq = lane >> 4;

    int nbx = gridDim.x;
    int orig = blockIdx.x + nbx * blockIdx.y;
    int nwg  = nbx * gridDim.y;
    int swz  = (nwg & 7) ? orig : ((orig & 7) * (nwg >> 3) + (orig >> 3));
    int bx = swz % nbx, by = swz / nbx;
    int m0 = by * 128, n0 = bx * 128;

    floatx4 acc[4][4] = {};

    const _Float16* ga[2]; const _Float16* gb[2];
    int loff[2];
#pragma unroll
    for (int i2 = 0; i2 < 2; ++i2) {
        int ch = 2 * w + i2;
        int row = ch * 16 + (lane >> 2), col = (lane & 3) * 8;
        ga[i2] = A  + (size_t)(m0 + row) * Kd + col;
        gb[i2] = Bt + (size_t)(n0 + row) * Kd + col;
        loff[i2] = ch * 512;
    }

    int nIter = Kd >> 5;
#pragma unroll
    for (int i2 = 0; i2 < 2; ++i2) {
        gl_lds16(ga[i2], &Als[0][loff[i2]]);
        gl_lds16(gb[i2], &Bls[0][loff[i2]]);
    }

    for (int it = 0; it < nIter; ++it) {
        int cur = it & 1;
        __syncthreads();               // buf[cur] staged; buf[cur^1] free
        if (it + 1 < nIter) {
            int k1 = (it + 1) << 5;
#pragma unroll
            for (int i2 = 0; i2 < 2; ++i2) {
                gl_lds16(ga[i2] + k1, &Als[cur ^ 1][loff[i2]]);
                gl_lds16(gb[i2] + k1, &Bls[cur ^ 1][loff[i2]]);
            }
        }
        const _Float16* Ab = Als[cur];
        const _Float16* Bb = Bls[cur];
        half8 af[4], bf[4];
#pragma unroll
        for (int i = 0; i < 4; ++i)
            af[i] = *(const half8*)(Ab + (wr * 64 + i * 16 + fr) * 32 + fq * 8);
#pragma unroll
        for (int j = 0; j < 4; ++j)
            bf[j] = *(const half8*)(Bb + (wc * 64 + j * 16 + fr) * 32 + fq * 8);
#pragma unroll
        for (int i = 0; i < 4; ++i)
#pragma unroll
            for (int j = 0; j < 4; ++j)
                acc[i][j] = __builtin_amdgcn_mfma_f32_16x16x32_f16(
                    af[i], bf[j], acc[i][j], 0, 0, 0);
    }

#pragma unroll
    for (int i = 0; i < 4; ++i)
#pragma unroll
        for (int j = 0; j < 4; ++j)
#pragma unroll
            for (int r2 = 0; r2 < 4; ++r2) {
                int row = m0 + wr * 64 + i * 16 + fq * 4 + r2;
                int col = n0 + wc * 64 + j * 16 + fr;
                Ch[(size_t)row * N + col] = (_Float16)(acc[i][j][r2] + bias[col]);
            }
}

// ---------- f16 MFMA GEMM 64x64, dbuf: Cf(f32) = A@Bt^T + bias + resid -----
// 4 waves, each 32x32 (2x2 frags). grid (N/64, M/64) -> 4 blocks/CU.
__global__ __launch_bounds__(256) void gemm64_f16_mfma(
    const _Float16* __restrict__ A, const _Float16* __restrict__ Bt,
    const float* __restrict__ bias, const float* __restrict__ resid,
    float* __restrict__ Cf, int M, int N, int Kd)
{
    __shared__ _Float16 Als[2][2048];
    __shared__ _Float16 Bls[2][2048];
    int tid = threadIdx.x, lane = tid & 63, w = tid >> 6;
    int wr = w >> 1, wc = w & 1;
    int fr = lane & 15, fq = lane >> 4;

    int nbx = gridDim.x;
    int orig = blockIdx.x + nbx * blockIdx.y;
    int nwg  = nbx * gridDim.y;
    int swz  = (nwg & 7) ? orig : ((orig & 7) * (nwg >> 3) + (orig >> 3));
    int bx = swz % nbx, by = swz / nbx;
    int m0 = by * 64, n0 = bx * 64;

    floatx4 acc[2][2] = {};

    int srow = w * 16 + (lane >> 2), scol = (lane & 3) * 8;
    const _Float16* ga = A  + (size_t)(m0 + srow) * Kd + scol;
    const _Float16* gb = Bt + (size_t)(n0 + srow) * Kd + scol;
    int loff = w * 512;

    int nIter = Kd >> 5;
    gl_lds16(ga, &Als[0][loff]);
    gl_lds16(gb, &Bls[0][loff]);

    for (int it = 0; it < nIter; ++it) {
        int cur = it & 1;
        __syncthreads();
        if (it + 1 < nIter) {
            int k1 = (it + 1) << 5;
            gl_lds16(ga + k1, &Als[cur ^ 1][loff]);
            gl_lds16(gb + k1, &Bls[cur ^ 1][loff]);
        }
        const _Float16* Ab = Als[cur];
        const _Float16* Bb = Bls[cur];
        half8 af[2], bf[2];
#pragma unroll
        for (int i = 0; i < 2; ++i)
            af[i] = *(const half8*)(Ab + (wr * 32 + i * 16 + fr) * 32 + fq * 8);
#pragma unroll
        for (int j = 0; j < 2; ++j)
            bf[j] = *(const half8*)(Bb + (wc * 32 + j * 16 + fr) * 32 + fq * 8);
#pragma unroll
        for (int i = 0; i < 2; ++i)
#pragma unroll
            for (int j = 0; j < 2; ++j)
                acc[i][j] = __builtin_amdgcn_mfma_f32_16x16x32_f16(
                    af[i], bf[j], acc[i][j], 0, 0, 0);
    }

#pragma unroll
    for (int i = 0; i < 2; ++i)
#pragma unroll
        for (int j = 0; j < 2; ++j)
#pragma unroll
            for (int r2 = 0; r2 < 4; ++r2) {
                int row = m0 + wr * 32 + i * 16 + fq * 4 + r2;
                int col = n0 + wc * 32 + j * 16 + fr;
                Cf[(size_t)row * N + col] =
                    acc[i][j][r2] + bias[col] + resid[(size_t)row * N + col];
            }
}

// ------- fused prep1: k-norm + RoPE -> qt/kt f16; V -> vt2 image -----------
__global__ __launch_bounds__(256) void prep1_kernel(
    const _Float16* __restrict__ qkvh, const float* __restrict__ pos,
    _Float16* __restrict__ qt, _Float16* __restrict__ kt,
    _Float16* __restrict__ vt2)
{
    __shared__ float tile[64][65];
    int head = blockIdx.x, tau = blockIdx.y;
    int s0 = tau * 64;
    int b = head >> 4, rh = head & 15;
    int lane = threadIdx.x & 63, w = threadIdx.x >> 6;

#pragma unroll
    for (int si = w; si < 64; si += 4)
        tile[si][lane] =
            (float)qkvh[(size_t)(b * S_ + s0 + si) * NQKV + rh * 192 + 128 + lane];
    __syncthreads();
    {
        int P = lane;
        int op = P >> 3;
        int hi = (P >> 2) & 1, lo = P & 3;
#pragma unroll
        for (int d = w; d < 64; d += 4) {
            int ol = op ^ (d & 7);
            int key = 32 * (ol >> 2) + 16 * hi + 4 * (ol & 3) + lo;
            vt2[(((size_t)head * 32 + tau) * 64 + d) * 64 + P] = (_Float16)tile[key][d];
        }
    }

    for (int i = 0; i < 16; ++i) {
        int s = s0 + w * 16 + i;
        int bs = b * S_ + s;
        const _Float16* base = qkvh + (size_t)bs * NQKV + rh * 192;
        float qv = (float)base[lane];
        float kv = (float)base[64 + lane];

        float ss = kv * kv;
#pragma unroll
        for (int off = 32; off > 0; off >>= 1) ss += __shfl_xor(ss, off);
        kv *= rsqrtf(ss);

        int j = lane & 31;
        float sn = pos[(size_t)bs * 64 + j];
        float cs = pos[(size_t)bs * 64 + 32 + j];
        float qp = __shfl_xor(qv, 32);
        float kp = __shfl_xor(kv, 32);
        float qo, ko;
        if (lane < 32) { qo = qv * cs - qp * sn; ko = kv * cs - kp * sn; }
        else           { qo = qp * sn + qv * cs; ko = kp * sn + kv * cs; }

        size_t oidx = ((size_t)head * S_ + s) * 64 + lane;
        qt[oidx] = (_Float16)(qo * LOG2E);   // fold log2(e) into q~
        kt[oidx] = (_Float16)ko;
    }
}

// ------- transposed MFMA flash attention, 8-wave blocks, KVBLK=256 ---------
// grid (8 q-tiles of 256, 32 heads) [qtile-fastest], block 512 = 8 waves;
// wave w owns 32 queries (2 q-groups of 16) at q0 + w*32. 8 intervals x 256
// keys (4 sub-tiles of 64) cover all 2048 keys. K/V double-buffered in LDS
// (128 KB); 8 waves share the tile; per wave 1 K-chunk + 1 V-chunk per
// sub-tile = 8 gl_lds/interval. Static-max softmax; normalization in
// epilogue; writes ctx directly.
// XCD swizzle: chunk of 32 blocks = 4 heads x 8 qtiles -> 2 MB K/V per L2.
__global__ __launch_bounds__(512) void attn_mfma_kernel(
    const _Float16* __restrict__ qt, const _Float16* __restrict__ kt,
    const _Float16* __restrict__ vt2, _Float16* __restrict__ ctx)
{
    __shared__ _Float16 Kls[2][16384];
    __shared__ _Float16 Vls[2][16384];

    int orig = blockIdx.x + 8 * blockIdx.y;        // 256 blocks
    int swz  = (orig & 7) * 32 + (orig >> 3);
    int q0   = (swz & 7) * 256;
    int head = swz >> 3;

    int b = head >> 4, rh = head & 15;
    int tid = threadIdx.x, lane = tid & 63, w = tid >> 6;   // w in [0,8)
    int g = lane >> 4, c = lane & 15;

    // Q B-frags + static softmax bound mL = |q~| (log2 units) per q-group
    half8 qf[2][2];
    floatx4 mz[2];                  // broadcast(-mL) for MFMA C-init
    float l_s[2] = {0.f, 0.f};
#pragma unroll
    for (int qg = 0; qg < 2; ++qg) {
        const _Float16* qp =
            qt + ((size_t)head * S_ + q0 + w * 32 + qg * 16 + c) * 64 + 8 * g;
        qf[qg][0] = *(const half8*)qp;
        qf[qg][1] = *(const half8*)(qp + 32);
        float qq = 0.f;
#pragma unroll
        for (int i = 0; i < 8; ++i) {
            float a = (float)qf[qg][0][i], b2 = (float)qf[qg][1][i];
            qq += a * a + b2 * b2;
        }
        qq += __shfl_xor(qq, 16);
        qq += __shfl_xor(qq, 32);
        float nm = -sqrtf(qq);    // s_log2 <= |q~|*|k^| (k^ unit norm)
        mz[qg][0] = nm; mz[qg][1] = nm; mz[qg][2] = nm; mz[qg][3] = nm;
    }

    floatx4 o_acc[2][4] = {};

    // staging geometry: wave w stages K chunk w and V chunk w of each
    // sub-tile (chunk = 8 keys x 64 d = 512 f16, staged 16B/lane).
    int krow = w * 8 + (lane >> 3);
    int koct = (lane & 7) ^ (lane >> 3);
    const _Float16* kg = kt + ((size_t)head * S_ + krow) * 64 + koct * 8;
    const _Float16* vg = vt2 + ((size_t)head * 32) * 4096 + w * 512 + lane * 8;
    int loff = w * 512;

    int co = c & 7;        // XOR swizzle term for frag reads

    // prologue: stage sub-tiles 0..3 into buffer 0
#pragma unroll
    for (int s = 0; s < 4; ++s) {
        gl_lds16(kg + (size_t)s * 4096, &Kls[0][s * 4096 + loff]);
        gl_lds16(vg + (size_t)s * 4096, &Vls[0][s * 4096 + loff]);
    }

    for (int jt = 0; jt < 8; ++jt) {
        int cur = jt & 1;
        __syncthreads();       // buf[cur] staged (4 sub-tiles); buf[cur^1] free
        if (jt + 1 < 8) {
#pragma unroll
            for (int s = 0; s < 4; ++s) {
                size_t joff = (size_t)(4 * (jt + 1) + s) * 4096;
                gl_lds16(kg + joff, &Kls[cur ^ 1][s * 4096 + loff]);
                gl_lds16(vg + joff, &Vls[cur ^ 1][s * 4096 + loff]);
            }
        }

#pragma unroll
        for (int s = 0; s < 4; ++s) {
            const _Float16* Kbuf = &Kls[cur][s * 4096];
            const _Float16* Vbuf = &Vls[cur][s * 4096];

            // ---- K fragments once, shared by both q-groups ----
            half8 kfr[8];
#pragma unroll
            for (int t = 0; t < 4; ++t) {
                const _Float16* krw = Kbuf + (16 * t + c) * 64;
                kfr[2 * t]     = *(const half8*)(krw + ((g) ^ co) * 8);
                kfr[2 * t + 1] = *(const half8*)(krw + ((4 + g) ^ co) * 8);
            }

            union { half8 v; fp16x2 h2[4]; } pf[2][2];
#pragma unroll
            for (int qg = 0; qg < 2; ++qg) {
                floatx4 sacc[4];
#pragma unroll
                for (int t = 0; t < 4; ++t) {
                    floatx4 z = mz[qg];   // C-init = -mL : sacc = S - mL
                    z = __builtin_amdgcn_mfma_f32_16x16x32_f16(
                        kfr[2 * t], qf[qg][0], z, 0, 0, 0);
                    z = __builtin_amdgcn_mfma_f32_16x16x32_f16(
                        kfr[2 * t + 1], qf[qg][1], z, 0, 0, 0);
                    sacc[t] = z;
                }
                float ps = 0.f;
#pragma unroll
                for (int t = 0; t < 4; ++t)
#pragma unroll
                    for (int r = 0; r < 4; ++r) {
                        float p = EXP2(sacc[t][r]);
                        sacc[t][r] = p;
                        ps += p;
                    }
                l_s[qg] += ps;
                pf[qg][0].h2[0] = __builtin_amdgcn_cvt_pkrtz(sacc[0][0], sacc[0][1]);
                pf[qg][0].h2[1] = __builtin_amdgcn_cvt_pkrtz(sacc[0][2], sacc[0][3]);
                pf[qg][0].h2[2] = __builtin_amdgcn_cvt_pkrtz(sacc[1][0], sacc[1][1]);
                pf[qg][0].h2[3] = __builtin_amdgcn_cvt_pkrtz(sacc[1][2], sacc[1][3]);
                pf[qg][1].h2[0] = __builtin_amdgcn_cvt_pkrtz(sacc[2][0], sacc[2][1]);
                pf[qg][1].h2[1] = __builtin_amdgcn_cvt_pkrtz(sacc[2][2], sacc[2][3]);
                pf[qg][1].h2[2] = __builtin_amdgcn_cvt_pkrtz(sacc[3][0], sacc[3][1]);
                pf[qg][1].h2[3] = __builtin_amdgcn_cvt_pkrtz(sacc[3][2], sacc[3][3]);
            }

            // ---- V fragments once, shared; O^T += V^T @ P^T ----
#pragma unroll
            for (int t = 0; t < 4; ++t) {
                const _Float16* vrow = Vbuf + (16 * t + c) * 64;
                half8 v0 = *(const half8*)(vrow + ((g) ^ co) * 8);
                half8 v1 = *(const half8*)(vrow + ((4 + g) ^ co) * 8);
#pragma unroll
                for (int qg = 0; qg < 2; ++qg) {
                    o_acc[qg][t] = __builtin_amdgcn_mfma_f32_16x16x32_f16(
                        v0, pf[qg][0].v, o_acc[qg][t], 0, 0, 0);
                    o_acc[qg][t] = __builtin_amdgcn_mfma_f32_16x16x32_f16(
                        v1, pf[qg][1].v, o_acc[qg][t], 0, 0, 0);
                }
            }
        }
    }

    // ---- epilogue: normalize (f32) and write ctx directly ----
#pragma unroll
    for (int qg = 0; qg < 2; ++qg) {
        float lt = l_s[qg];
        lt += __shfl_xor(lt, 16);
        lt += __shfl_xor(lt, 32);
        float inv = 1.f / lt;
        int q = q0 + w * 32 + qg * 16 + c;
        size_t rowbase = (size_t)(b * S_ + q) * 1024 + rh * 64;
#pragma unroll
        for (int t = 0; t < 4; ++t) {
            union { half4 v; fp16x2 h2[2]; } e;
            e.h2[0] = __builtin_amdgcn_cvt_pkrtz(o_acc[qg][t][0] * inv,
                                                 o_acc[qg][t][1] * inv);
            e.h2[1] = __builtin_amdgcn_cvt_pkrtz(o_acc[qg][t][2] * inv,
                                                 o_acc[qg][t][3] * inv);
            *(half4*)(ctx + rowbase + 16 * t + 4 * g) = e.v;
        }
    }
}

// --------------------- LayerNorm in place on y[4096][1024] -----------------
__global__ __launch_bounds__(256) void ln_kernel(
    float* __restrict__ y, const float* __restrict__ g, const float* __restrict__ bb)
{
    int row = blockIdx.x, tid = threadIdx.x;
    float* p = y + (size_t)row * 1024;
    float4 v = ((const float4*)p)[tid];
    float sum = v.x + v.y + v.z + v.w;
    float sq  = v.x*v.x + v.y*v.y + v.z*v.z + v.w*v.w;
#pragma unroll
    for (int off = 32; off > 0; off >>= 1) {
        sum += __shfl_xor(sum, off);
        sq  += __shfl_xor(sq,  off);
    }
    __shared__ float rs[4], rq[4];
    int w = tid >> 6;
    if ((tid & 63) == 0) { rs[w] = sum; rq[w] = sq; }
    __syncthreads();
    sum = rs[0] + rs[1] + rs[2] + rs[3];
    sq  = rq[0] + rq[1] + rq[2] + rq[3];
    float mean = sum * (1.f / 1024.f);
    float var  = sq * (1.f / 1024.f) - mean * mean;
    float inv  = rsqrtf(var + 1e-5f);
    float4 gv = ((const float4*)g)[tid];
    float4 bv = ((const float4*)bb)[tid];
    v.x = (v.x - mean) * inv * gv.x + bv.x;
    v.y = (v.y - mean) * inv * gv.y + bv.y;
    v.z = (v.z - mean) * inv * gv.z + bv.z;
    v.w = (v.w - mean) * inv * gv.w + bv.w;
    ((float4*)p)[tid] = v;
}

// ---------------------------------------------------------------------------
extern "C" void kernel_launch(void* const* d_in, const int* in_sizes, int n_in,
                              void* d_out, int out_size, void* d_ws, size_t ws_size,
                              hipStream_t stream)
{
    const float* x     = (const float*)d_in[0];
    const float* pos   = (const float*)d_in[1];
    const float* W_qkv = (const float*)d_in[2];
    const float* b_qkv = (const float*)d_in[3];
    const float* W_out = (const float*)d_in[4];
    const float* b_out = (const float*)d_in[5];
    const float* ln_g  = (const float*)d_in[6];
    const float* ln_b  = (const float*)d_in[7];
    float* out = (float*)d_out;

    // workspace layout — 64 MB peak via time-disjoint aliasing:
    //   [ 0, 8)   x_h   (steps 1-2)   then ctx   (steps 4-6, attn writes it)
    //   [ 8,14)   wqkv_t (steps 1-2)
    //   [14,16)   wout_t (steps 1-6)
    //   [16,40)   qkvh  (steps 2-3)
    //   [40,48)   qt    (steps 3-4)
    //   [48,56)   kt    (steps 3-4)
    //   [56,64)   vt2   (steps 3-4)
    char* ws = (char*)d_ws;
    _Float16* x_h    = (_Float16*)(ws);
    _Float16* ctx_h  = (_Float16*)(ws);                       // alias x_h
    _Float16* wqkv_t = (_Float16*)(ws + ((size_t)8  << 20));
    _Float16* wout_t = (_Float16*)(ws + ((size_t)14 << 20));
    _Float16* qkvh   = (_Float16*)(ws + ((size_t)16 << 20));
    _Float16* qt_h   = (_Float16*)(ws + ((size_t)40 << 20));
    _Float16* kt_h   = (_Float16*)(ws + ((size_t)48 << 20));
    _Float16* vt2_h  = (_Float16*)(ws + ((size_t)56 << 20));

    // 1) fused cast + weight transposes
    prep0_kernel<<<8192, 256, 0, stream>>>(x, x_h, W_qkv, wqkv_t, W_out, wout_t);

    // 2) qkv (f16) = x @ W_qkv + b_qkv
    gemm_f16_mfma<<<dim3(NQKV / 128, BS_ / 128), 256, 0, stream>>>(
        x_h, wqkv_t, b_qkv, qkvh, BS_, NQKV, H_);

    // 3) fused k-norm + RoPE + V-image
    prep1_kernel<<<dim3(32, 32), 256, 0, stream>>>(qkvh, pos, qt_h, kt_h, vt2_h);

    // 4) MFMA flash attention (8-wave blocks, KVBLK=256) -> ctx f16
    attn_mfma_kernel<<<dim3(8, 32), 512, 0, stream>>>(
        qt_h, kt_h, vt2_h, ctx_h);

    // 5) out (fp32) = x + ctx @ W_out + b_out   (64x64 tiles, 4 blocks/CU)
    gemm64_f16_mfma<<<dim3(H_ / 64, BS_ / 64), 256, 0, stream>>>(
        ctx_h, wout_t, b_out, x, out, BS_, H_, H_);

    // 6) LayerNorm in place
    ln_kernel<<<BS_, 256, 0, stream>>>(out, ln_g, ln_b);
}

// Round 11
// 200.979 us; speedup vs baseline: 1.4121x; 1.0253x over previous
//
#include <hip/hip_runtime.h>

// ---------------------------------------------------------------------------
// SelfMultiHeadAttn: x[B,S,H] -> LN(x + OutProj(SDPA(RoPE(q), RoPE(k/|k|), v)))
// B=2 S=2048 H=1024 R=16 heads, K=64 head dim. fp32 in/out.
// Ledger: R12 224.7 | R13 ✗ | R14 ✗ | R15 223.2 | R16 221.2 WIN | R17 212.9
//         WIN | R18 209.8 WIN | R19 ✗✗ 283.8 (spills) | R20 206.1 (R18
//         revert verified; attn 42.3).
// R21 = R20 + prep1 vectorized (single change): q/k path had SCALAR f16
//       loads/stores (Common-mistake #2, ~2.3 TB/s) -> half8 loads, shfl
//       row-reduce for k-norm, lane^4 shuffle for RoPE pair, float4 pos,
//       half8 packed stores. V-tile load also half8. Same math (k-norm sum
//       order differs; well under tolerance).
// ---------------------------------------------------------------------------

#define B_   2
#define S_   2048
#define H_   1024
#define R_   16
#define BS_  (B_*S_)     // 4096 rows
#define NQKV 3072        // R*K*3
#define LOG2E 1.44269504088896f

typedef float    floatx4 __attribute__((ext_vector_type(4)));
typedef _Float16 half8   __attribute__((ext_vector_type(8)));
typedef _Float16 half4   __attribute__((ext_vector_type(4)));
typedef __fp16   fp16x2  __attribute__((ext_vector_type(2)));  // cvt_pkrtz ret

#if __has_builtin(__builtin_amdgcn_exp2f)
#define EXP2(x) __builtin_amdgcn_exp2f(x)
#else
#define EXP2(x) exp2f(x)
#endif

// async global -> LDS, 16 B per lane (lds dest = wave-uniform base + lane*16)
__device__ __forceinline__ void gl_lds16(const _Float16* g, _Float16* l) {
    __builtin_amdgcn_global_load_lds(
        (const __attribute__((address_space(1))) unsigned int*)g,
        (__attribute__((address_space(3))) unsigned int*)l, 16, 0, 0);
}

// ------- fused preprocessing: x cast + W_qkv^T + W_out^T (one launch) ------
// grid 8192: [0,4096) cast x; [4096,7168) W_qkv transpose; [7168,8192) W_out.
__global__ __launch_bounds__(256) void prep0_kernel(
    const float* __restrict__ x, _Float16* __restrict__ x_h,
    const float* __restrict__ W_qkv, _Float16* __restrict__ wqkv_t,
    const float* __restrict__ W_out, _Float16* __restrict__ wout_t)
{
    __shared__ float tile[32][33];
    int bid = blockIdx.x, tid = threadIdx.x;
    if (bid < 4096) {
        int i = bid * 1024 + tid * 4;
        float4 v = *(const float4*)(x + i);
        half4 h;
        h.x = (_Float16)v.x; h.y = (_Float16)v.y;
        h.z = (_Float16)v.z; h.w = (_Float16)v.w;
        *(half4*)(x_h + i) = h;
        return;
    }
    const float* in; _Float16* out; int rows, cols, bx, by;
    if (bid < 7168) {
        int t = bid - 4096;
        in = W_qkv; out = wqkv_t; rows = H_; cols = NQKV;
        bx = t % 96; by = t / 96;
    } else {
        int t = bid - 7168;
        in = W_out; out = wout_t; rows = H_; cols = H_;
        bx = t & 31; by = t >> 5;
    }
    int cx = bx * 32, ry = by * 32;
    int tx = tid & 31, ty = tid >> 5;   // ty 0..7
#pragma unroll
    for (int i = 0; i < 32; i += 8)
        tile[ty + i][tx] = in[(size_t)(ry + ty + i) * cols + cx + tx];
    __syncthreads();
#pragma unroll
    for (int i = 0; i < 32; i += 8)
        out[(size_t)(cx + ty + i) * rows + ry + tx] = (_Float16)tile[tx][ty + i];
}

// ---------- f16 MFMA GEMM 128x128, dbuf:  Ch(f16) = A @ Bt^T + bias --------
__global__ __launch_bounds__(256) void gemm_f16_mfma(
    const _Float16* __restrict__ A, const _Float16* __restrict__ Bt,
    const float* __restrict__ bias, _Float16* __restrict__ Ch,
    int M, int N, int Kd)
{
    __shared__ _Float16 Als[2][4096];
    __shared__ _Float16 Bls[2][4096];
    int tid  = threadIdx.x;
    int lane = tid & 63, w = tid >> 6;
    int wr = w >> 1, wc = w & 1;
    int fr = lane & 15, fq = lane >> 4;

    int nbx = gridDim.x;
    int orig = blockIdx.x + nbx * blockIdx.y;
    int nwg  = nbx * gridDim.y;
    int swz  = (nwg & 7) ? orig : ((orig & 7) * (nwg >> 3) + (orig >> 3));
    int bx = swz % nbx, by = swz / nbx;
    int m0 = by * 128, n0 = bx * 128;

    floatx4 acc[4][4] = {};

    const _Float16* ga[2]; const _Float16* gb[2];
    int loff[2];
#pragma unroll
    for (int i2 = 0; i2 < 2; ++i2) {
        int ch = 2 * w + i2;
        int row = ch * 16 + (lane >> 2), col = (lane & 3) * 8;
        ga[i2] = A  + (size_t)(m0 + row) * Kd + col;
        gb[i2] = Bt + (size_t)(n0 + row) * Kd + col;
        loff[i2] = ch * 512;
    }

    int nIter = Kd >> 5;
#pragma unroll
    for (int i2 = 0; i2 < 2; ++i2) {
        gl_lds16(ga[i2], &Als[0][loff[i2]]);
        gl_lds16(gb[i2], &Bls[0][loff[i2]]);
    }

    for (int it = 0; it < nIter; ++it) {
        int cur = it & 1;
        __syncthreads();               // buf[cur] staged; buf[cur^1] free
        if (it + 1 < nIter) {
            int k1 = (it + 1) << 5;
#pragma unroll
            for (int i2 = 0; i2 < 2; ++i2) {
                gl_lds16(ga[i2] + k1, &Als[cur ^ 1][loff[i2]]);
                gl_lds16(gb[i2] + k1, &Bls[cur ^ 1][loff[i2]]);
            }
        }
        const _Float16* Ab = Als[cur];
        const _Float16* Bb = Bls[cur];
        half8 af[4], bf[4];
#pragma unroll
        for (int i = 0; i < 4; ++i)
            af[i] = *(const half8*)(Ab + (wr * 64 + i * 16 + fr) * 32 + fq * 8);
#pragma unroll
        for (int j = 0; j < 4; ++j)
            bf[j] = *(const half8*)(Bb + (wc * 64 + j * 16 + fr) * 32 + fq * 8);
#pragma unroll
        for (int i = 0; i < 4; ++i)
#pragma unroll
            for (int j = 0; j < 4; ++j)
                acc[i][j] = __builtin_amdgcn_mfma_f32_16x16x32_f16(
                    af[i], bf[j], acc[i][j], 0, 0, 0);
    }

#pragma unroll
    for (int i = 0; i < 4; ++i)
#pragma unroll
        for (int j = 0; j < 4; ++j)
#pragma unroll
            for (int r2 = 0; r2 < 4; ++r2) {
                int row = m0 + wr * 64 + i * 16 + fq * 4 + r2;
                int col = n0 + wc * 64 + j * 16 + fr;
                Ch[(size_t)row * N + col] = (_Float16)(acc[i][j][r2] + bias[col]);
            }
}

// ---------- f16 MFMA GEMM 64x64, dbuf: Cf(f32) = A@Bt^T + bias + resid -----
// 4 waves, each 32x32 (2x2 frags). grid (N/64, M/64) -> 4 blocks/CU.
__global__ __launch_bounds__(256) void gemm64_f16_mfma(
    const _Float16* __restrict__ A, const _Float16* __restrict__ Bt,
    const float* __restrict__ bias, const float* __restrict__ resid,
    float* __restrict__ Cf, int M, int N, int Kd)
{
    __shared__ _Float16 Als[2][2048];
    __shared__ _Float16 Bls[2][2048];
    int tid = threadIdx.x, lane = tid & 63, w = tid >> 6;
    int wr = w >> 1, wc = w & 1;
    int fr = lane & 15, fq = lane >> 4;

    int nbx = gridDim.x;
    int orig = blockIdx.x + nbx * blockIdx.y;
    int nwg  = nbx * gridDim.y;
    int swz  = (nwg & 7) ? orig : ((orig & 7) * (nwg >> 3) + (orig >> 3));
    int bx = swz % nbx, by = swz / nbx;
    int m0 = by * 64, n0 = bx * 64;

    floatx4 acc[2][2] = {};

    int srow = w * 16 + (lane >> 2), scol = (lane & 3) * 8;
    const _Float16* ga = A  + (size_t)(m0 + srow) * Kd + scol;
    const _Float16* gb = Bt + (size_t)(n0 + srow) * Kd + scol;
    int loff = w * 512;

    int nIter = Kd >> 5;
    gl_lds16(ga, &Als[0][loff]);
    gl_lds16(gb, &Bls[0][loff]);

    for (int it = 0; it < nIter; ++it) {
        int cur = it & 1;
        __syncthreads();
        if (it + 1 < nIter) {
            int k1 = (it + 1) << 5;
            gl_lds16(ga + k1, &Als[cur ^ 1][loff]);
            gl_lds16(gb + k1, &Bls[cur ^ 1][loff]);
        }
        const _Float16* Ab = Als[cur];
        const _Float16* Bb = Bls[cur];
        half8 af[2], bf[2];
#pragma unroll
        for (int i = 0; i < 2; ++i)
            af[i] = *(const half8*)(Ab + (wr * 32 + i * 16 + fr) * 32 + fq * 8);
#pragma unroll
        for (int j = 0; j < 2; ++j)
            bf[j] = *(const half8*)(Bb + (wc * 32 + j * 16 + fr) * 32 + fq * 8);
#pragma unroll
        for (int i = 0; i < 2; ++i)
#pragma unroll
            for (int j = 0; j < 2; ++j)
                acc[i][j] = __builtin_amdgcn_mfma_f32_16x16x32_f16(
                    af[i], bf[j], acc[i][j], 0, 0, 0);
    }

#pragma unroll
    for (int i = 0; i < 2; ++i)
#pragma unroll
        for (int j = 0; j < 2; ++j)
#pragma unroll
            for (int r2 = 0; r2 < 4; ++r2) {
                int row = m0 + wr * 32 + i * 16 + fq * 4 + r2;
                int col = n0 + wc * 32 + j * 16 + fr;
                Cf[(size_t)row * N + col] =
                    acc[i][j][r2] + bias[col] + resid[(size_t)row * N + col];
            }
}

// ------- fused prep1 (VECTORIZED): k-norm + RoPE -> qt/kt; V -> vt2 image --
// grid (head 32, s-tile 32), block 256 = 4 waves. Lane decomposition for the
// vector path: lane = 8*r + b8 -> row r (of 8 per pass), d-block b8 (8 elems).
// k-norm: in-lane 8-sum + shfl_xor(1,2,4) across the row's 8 lanes.
// RoPE pair d <-> d^32 lives at lane^4 (same row, same norm).
__global__ __launch_bounds__(256) void prep1_kernel(
    const _Float16* __restrict__ qkvh, const float* __restrict__ pos,
    _Float16* __restrict__ qt, _Float16* __restrict__ kt,
    _Float16* __restrict__ vt2)
{
    __shared__ float tile[64][65];
    int head = blockIdx.x, tau = blockIdx.y;
    int s0 = tau * 64;
    int b = head >> 4, rh = head & 15;
    int lane = threadIdx.x & 63, w = threadIdx.x >> 6;
    int r = lane >> 3, b8 = lane & 7;

    // ---- Part A: V tile -> LDS (half8 loads; wave w owns rows [w*16,w*16+16))
#pragma unroll
    for (int p = 0; p < 2; ++p) {
        int si = w * 16 + p * 8 + r;
        half8 v8 = *(const half8*)(qkvh + (size_t)(b * S_ + s0 + si) * NQKV
                                   + rh * 192 + 128 + b8 * 8);
#pragma unroll
        for (int e = 0; e < 8; ++e)
            tile[si][b8 * 8 + e] = (float)v8[e];
    }
    __syncthreads();
    // ---- V image write (keymap + bank XOR baked), unchanged ----
    {
        int P = lane;
        int op = P >> 3;
        int hi = (P >> 2) & 1, lo = P & 3;
#pragma unroll
        for (int d = w; d < 64; d += 4) {
            int ol = op ^ (d & 7);
            int key = 32 * (ol >> 2) + 16 * hi + 4 * (ol & 3) + lo;
            vt2[(((size_t)head * 32 + tau) * 64 + d) * 64 + P] = (_Float16)tile[key][d];
        }
    }

    // ---- Part B: q/k k-norm + RoPE, half8 vector path ----
#pragma unroll
    for (int p = 0; p < 2; ++p) {
        int s = s0 + w * 16 + p * 8 + r;
        int bs = b * S_ + s;
        const _Float16* base = qkvh + (size_t)bs * NQKV + rh * 192 + b8 * 8;
        union { half8 v; int i[4]; } q8, k8, qp8, kp8;
        q8.v = *(const half8*)(base);
        k8.v = *(const half8*)(base + 64);

        // k row norm: 8 lanes (same r) hold the 64 k-values
        float ss = 0.f;
#pragma unroll
        for (int e = 0; e < 8; ++e) { float kv = (float)k8.v[e]; ss += kv * kv; }
        ss += __shfl_xor(ss, 1);
        ss += __shfl_xor(ss, 2);
        ss += __shfl_xor(ss, 4);
        float rinv = rsqrtf(ss);

        // RoPE partner block (d ^ 32) = lane ^ 4 (same row -> same rinv)
#pragma unroll
        for (int e2 = 0; e2 < 4; ++e2) {
            qp8.i[e2] = __shfl_xor(q8.i[e2], 4);
            kp8.i[e2] = __shfl_xor(k8.i[e2], 4);
        }

        const float* pp = pos + (size_t)bs * 64 + (b8 & 3) * 8;
        float4 sn0 = *(const float4*)(pp);
        float4 sn1 = *(const float4*)(pp + 4);
        float4 cs0 = *(const float4*)(pp + 32);
        float4 cs1 = *(const float4*)(pp + 36);
        float sn[8] = {sn0.x, sn0.y, sn0.z, sn0.w, sn1.x, sn1.y, sn1.z, sn1.w};
        float cs[8] = {cs0.x, cs0.y, cs0.z, cs0.w, cs1.x, cs1.y, cs1.z, cs1.w};

        bool lo = (b8 < 4);
        float qo[8], ko[8];
#pragma unroll
        for (int e = 0; e < 8; ++e) {
            float qv = (float)q8.v[e];
            float qp = (float)qp8.v[e];
            float kv = (float)k8.v[e] * rinv;
            float kp = (float)kp8.v[e] * rinv;
            if (lo) { qo[e] = qv * cs[e] - qp * sn[e];
                      ko[e] = kv * cs[e] - kp * sn[e]; }
            else    { qo[e] = qp * sn[e] + qv * cs[e];
                      ko[e] = kp * sn[e] + kv * cs[e]; }
        }

        union { half8 v; fp16x2 h2[4]; } qe, ke;
#pragma unroll
        for (int e2 = 0; e2 < 4; ++e2) {
            qe.h2[e2] = __builtin_amdgcn_cvt_pkrtz(qo[2 * e2] * LOG2E,
                                                   qo[2 * e2 + 1] * LOG2E);
            ke.h2[e2] = __builtin_amdgcn_cvt_pkrtz(ko[2 * e2], ko[2 * e2 + 1]);
        }
        size_t oidx = ((size_t)head * S_ + s) * 64 + b8 * 8;
        *(half8*)(qt + oidx) = qe.v;
        *(half8*)(kt + oidx) = ke.v;
    }
}

// ------- transposed MFMA flash attention, 8-wave blocks, KVBLK=256 ---------
// grid (8 q-tiles of 256, 32 heads) [qtile-fastest], block 512 = 8 waves;
// wave w owns 32 queries (2 q-groups of 16) at q0 + w*32. 8 intervals x 256
// keys (4 sub-tiles of 64) cover all 2048 keys. K/V double-buffered in LDS
// (128 KB); 8 waves share the tile. Static-max softmax; normalization in
// epilogue; writes ctx directly.
// XCD swizzle: chunk of 32 blocks = 4 heads x 8 qtiles -> 2 MB K/V per L2.
__global__ __launch_bounds__(512) void attn_mfma_kernel(
    const _Float16* __restrict__ qt, const _Float16* __restrict__ kt,
    const _Float16* __restrict__ vt2, _Float16* __restrict__ ctx)
{
    __shared__ _Float16 Kls[2][16384];
    __shared__ _Float16 Vls[2][16384];

    int orig = blockIdx.x + 8 * blockIdx.y;        // 256 blocks
    int swz  = (orig & 7) * 32 + (orig >> 3);
    int q0   = (swz & 7) * 256;
    int head = swz >> 3;

    int b = head >> 4, rh = head & 15;
    int tid = threadIdx.x, lane = tid & 63, w = tid >> 6;   // w in [0,8)
    int g = lane >> 4, c = lane & 15;

    // Q B-frags + static softmax bound mL = |q~| (log2 units) per q-group
    half8 qf[2][2];
    floatx4 mz[2];                  // broadcast(-mL) for MFMA C-init
    float l_s[2] = {0.f, 0.f};
#pragma unroll
    for (int qg = 0; qg < 2; ++qg) {
        const _Float16* qp =
            qt + ((size_t)head * S_ + q0 + w * 32 + qg * 16 + c) * 64 + 8 * g;
        qf[qg][0] = *(const half8*)qp;
        qf[qg][1] = *(const half8*)(qp + 32);
        float qq = 0.f;
#pragma unroll
        for (int i = 0; i < 8; ++i) {
            float a = (float)qf[qg][0][i], b2 = (float)qf[qg][1][i];
            qq += a * a + b2 * b2;
        }
        qq += __shfl_xor(qq, 16);
        qq += __shfl_xor(qq, 32);
        float nm = -sqrtf(qq);    // s_log2 <= |q~|*|k^| (k^ unit norm)
        mz[qg][0] = nm; mz[qg][1] = nm; mz[qg][2] = nm; mz[qg][3] = nm;
    }

    floatx4 o_acc[2][4] = {};

    // staging geometry: wave w stages K chunk w and V chunk w of each
    // sub-tile (chunk = 8 keys x 64 d = 512 f16, staged 16B/lane).
    int krow = w * 8 + (lane >> 3);
    int koct = (lane & 7) ^ (lane >> 3);
    const _Float16* kg = kt + ((size_t)head * S_ + krow) * 64 + koct * 8;
    const _Float16* vg = vt2 + ((size_t)head * 32) * 4096 + w * 512 + lane * 8;
    int loff = w * 512;

    int co = c & 7;        // XOR swizzle term for frag reads

    // prologue: stage sub-tiles 0..3 into buffer 0
#pragma unroll
    for (int s = 0; s < 4; ++s) {
        gl_lds16(kg + (size_t)s * 4096, &Kls[0][s * 4096 + loff]);
        gl_lds16(vg + (size_t)s * 4096, &Vls[0][s * 4096 + loff]);
    }

    for (int jt = 0; jt < 8; ++jt) {
        int cur = jt & 1;
        __syncthreads();       // buf[cur] staged (4 sub-tiles); buf[cur^1] free
        if (jt + 1 < 8) {
#pragma unroll
            for (int s = 0; s < 4; ++s) {
                size_t joff = (size_t)(4 * (jt + 1) + s) * 4096;
                gl_lds16(kg + joff, &Kls[cur ^ 1][s * 4096 + loff]);
                gl_lds16(vg + joff, &Vls[cur ^ 1][s * 4096 + loff]);
            }
        }

#pragma unroll
        for (int s = 0; s < 4; ++s) {
            const _Float16* Kbuf = &Kls[cur][s * 4096];
            const _Float16* Vbuf = &Vls[cur][s * 4096];

            // ---- K fragments once, shared by both q-groups ----
            half8 kfr[8];
#pragma unroll
            for (int t = 0; t < 4; ++t) {
                const _Float16* krw = Kbuf + (16 * t + c) * 64;
                kfr[2 * t]     = *(const half8*)(krw + ((g) ^ co) * 8);
                kfr[2 * t + 1] = *(const half8*)(krw + ((4 + g) ^ co) * 8);
            }

            union { half8 v; fp16x2 h2[4]; } pf[2][2];
#pragma unroll
            for (int qg = 0; qg < 2; ++qg) {
                floatx4 sacc[4];
#pragma unroll
                for (int t = 0; t < 4; ++t) {
                    floatx4 z = mz[qg];   // C-init = -mL : sacc = S - mL
                    z = __builtin_amdgcn_mfma_f32_16x16x32_f16(
                        kfr[2 * t], qf[qg][0], z, 0, 0, 0);
                    z = __builtin_amdgcn_mfma_f32_16x16x32_f16(
                        kfr[2 * t + 1], qf[qg][1], z, 0, 0, 0);
                    sacc[t] = z;
                }
                float ps = 0.f;
#pragma unroll
                for (int t = 0; t < 4; ++t)
#pragma unroll
                    for (int r = 0; r < 4; ++r) {
                        float p = EXP2(sacc[t][r]);
                        sacc[t][r] = p;
                        ps += p;
                    }
                l_s[qg] += ps;
                pf[qg][0].h2[0] = __builtin_amdgcn_cvt_pkrtz(sacc[0][0], sacc[0][1]);
                pf[qg][0].h2[1] = __builtin_amdgcn_cvt_pkrtz(sacc[0][2], sacc[0][3]);
                pf[qg][0].h2[2] = __builtin_amdgcn_cvt_pkrtz(sacc[1][0], sacc[1][1]);
                pf[qg][0].h2[3] = __builtin_amdgcn_cvt_pkrtz(sacc[1][2], sacc[1][3]);
                pf[qg][1].h2[0] = __builtin_amdgcn_cvt_pkrtz(sacc[2][0], sacc[2][1]);
                pf[qg][1].h2[1] = __builtin_amdgcn_cvt_pkrtz(sacc[2][2], sacc[2][3]);
                pf[qg][1].h2[2] = __builtin_amdgcn_cvt_pkrtz(sacc[3][0], sacc[3][1]);
                pf[qg][1].h2[3] = __builtin_amdgcn_cvt_pkrtz(sacc[3][2], sacc[3][3]);
            }

            // ---- V fragments once, shared; O^T += V^T @ P^T ----
#pragma unroll
            for (int t = 0; t < 4; ++t) {
                const _Float16* vrow = Vbuf + (16 * t + c) * 64;
                half8 v0 = *(const half8*)(vrow + ((g) ^ co) * 8);
                half8 v1 = *(const half8*)(vrow + ((4 + g) ^ co) * 8);
#pragma unroll
                for (int qg = 0; qg < 2; ++qg) {
                    o_acc[qg][t] = __builtin_amdgcn_mfma_f32_16x16x32_f16(
                        v0, pf[qg][0].v, o_acc[qg][t], 0, 0, 0);
                    o_acc[qg][t] = __builtin_amdgcn_mfma_f32_16x16x32_f16(
                        v1, pf[qg][1].v, o_acc[qg][t], 0, 0, 0);
                }
            }
        }
    }

    // ---- epilogue: normalize (f32) and write ctx directly ----
#pragma unroll
    for (int qg = 0; qg < 2; ++qg) {
        float lt = l_s[qg];
        lt += __shfl_xor(lt, 16);
        lt += __shfl_xor(lt, 32);
        float inv = 1.f / lt;
        int q = q0 + w * 32 + qg * 16 + c;
        size_t rowbase = (size_t)(b * S_ + q) * 1024 + rh * 64;
#pragma unroll
        for (int t = 0; t < 4; ++t) {
            union { half4 v; fp16x2 h2[2]; } e;
            e.h2[0] = __builtin_amdgcn_cvt_pkrtz(o_acc[qg][t][0] * inv,
                                                 o_acc[qg][t][1] * inv);
            e.h2[1] = __builtin_amdgcn_cvt_pkrtz(o_acc[qg][t][2] * inv,
                                                 o_acc[qg][t][3] * inv);
            *(half4*)(ctx + rowbase + 16 * t + 4 * g) = e.v;
        }
    }
}

// --------------------- LayerNorm in place on y[4096][1024] -----------------
__global__ __launch_bounds__(256) void ln_kernel(
    float* __restrict__ y, const float* __restrict__ g, const float* __restrict__ bb)
{
    int row = blockIdx.x, tid = threadIdx.x;
    float* p = y + (size_t)row * 1024;
    float4 v = ((const float4*)p)[tid];
    float sum = v.x + v.y + v.z + v.w;
    float sq  = v.x*v.x + v.y*v.y + v.z*v.z + v.w*v.w;
#pragma unroll
    for (int off = 32; off > 0; off >>= 1) {
        sum += __shfl_xor(sum, off);
        sq  += __shfl_xor(sq,  off);
    }
    __shared__ float rs[4], rq[4];
    int w = tid >> 6;
    if ((tid & 63) == 0) { rs[w] = sum; rq[w] = sq; }
    __syncthreads();
    sum = rs[0] + rs[1] + rs[2] + rs[3];
    sq  = rq[0] + rq[1] + rq[2] + rq[3];
    float mean = sum * (1.f / 1024.f);
    float var  = sq * (1.f / 1024.f) - mean * mean;
    float inv  = rsqrtf(var + 1e-5f);
    float4 gv = ((const float4*)g)[tid];
    float4 bv = ((const float4*)bb)[tid];
    v.x = (v.x - mean) * inv * gv.x + bv.x;
    v.y = (v.y - mean) * inv * gv.y + bv.y;
    v.z = (v.z - mean) * inv * gv.z + bv.z;
    v.w = (v.w - mean) * inv * gv.w + bv.w;
    ((float4*)p)[tid] = v;
}

// ---------------------------------------------------------------------------
extern "C" void kernel_launch(void* const* d_in, const int* in_sizes, int n_in,
                              void* d_out, int out_size, void* d_ws, size_t ws_size,
                              hipStream_t stream)
{
    const float* x     = (const float*)d_in[0];
    const float* pos   = (const float*)d_in[1];
    const float* W_qkv = (const float*)d_in[2];
    const float* b_qkv = (const float*)d_in[3];
    const float* W_out = (const float*)d_in[4];
    const float* b_out = (const float*)d_in[5];
    const float* ln_g  = (const float*)d_in[6];
    const float* ln_b  = (const float*)d_in[7];
    float* out = (float*)d_out;

    // workspace layout — 64 MB peak via time-disjoint aliasing:
    //   [ 0, 8)   x_h   (steps 1-2)   then ctx   (steps 4-6, attn writes it)
    //   [ 8,14)   wqkv_t (steps 1-2)
    //   [14,16)   wout_t (steps 1-6)
    //   [16,40)   qkvh  (steps 2-3)
    //   [40,48)   qt    (steps 3-4)
    //   [48,56)   kt    (steps 3-4)
    //   [56,64)   vt2   (steps 3-4)
    char* ws = (char*)d_ws;
    _Float16* x_h    = (_Float16*)(ws);
    _Float16* ctx_h  = (_Float16*)(ws);                       // alias x_h
    _Float16* wqkv_t = (_Float16*)(ws + ((size_t)8  << 20));
    _Float16* wout_t = (_Float16*)(ws + ((size_t)14 << 20));
    _Float16* qkvh   = (_Float16*)(ws + ((size_t)16 << 20));
    _Float16* qt_h   = (_Float16*)(ws + ((size_t)40 << 20));
    _Float16* kt_h   = (_Float16*)(ws + ((size_t)48 << 20));
    _Float16* vt2_h  = (_Float16*)(ws + ((size_t)56 << 20));

    // 1) fused cast + weight transposes
    prep0_kernel<<<8192, 256, 0, stream>>>(x, x_h, W_qkv, wqkv_t, W_out, wout_t);

    // 2) qkv (f16) = x @ W_qkv + b_qkv
    gemm_f16_mfma<<<dim3(NQKV / 128, BS_ / 128), 256, 0, stream>>>(
        x_h, wqkv_t, b_qkv, qkvh, BS_, NQKV, H_);

    // 3) fused k-norm + RoPE + V-image (vectorized)
    prep1_kernel<<<dim3(32, 32), 256, 0, stream>>>(qkvh, pos, qt_h, kt_h, vt2_h);

    // 4) MFMA flash attention (8-wave blocks, KVBLK=256) -> ctx f16
    attn_mfma_kernel<<<dim3(8, 32), 512, 0, stream>>>(
        qt_h, kt_h, vt2_h, ctx_h);

    // 5) out (fp32) = x + ctx @ W_out + b_out   (64x64 tiles, 4 blocks/CU)
    gemm64_f16_mfma<<<dim3(H_ / 64, BS_ / 64), 256, 0, stream>>>(
        ctx_h, wout_t, b_out, x, out, BS_, H_, H_);

    // 6) LayerNorm in place
    ln_kernel<<<BS_, 256, 0, stream>>>(out, ln_g, ln_b);
}

// Round 12
// 197.774 us; speedup vs baseline: 1.4350x; 1.0162x over previous
//
#include <hip/hip_runtime.h>

// ---------------------------------------------------------------------------
// SelfMultiHeadAttn: x[B,S,H] -> LN(x + OutProj(SDPA(RoPE(q), RoPE(k/|k|), v)))
// B=2 S=2048 H=1024 R=16 heads, K=64 head dim. fp32 in/out.
// Ledger: R12 224.7 | R13 ✗ | R14 ✗ | R15 223.2 | R16 221.2 WIN | R17 212.9
//         WIN | R18 209.8 WIN | R19 ✗✗ spills | R20 206.1 | R21 201.0 WIN
//         (prep1 vectorized; attn 43.8 unchanged).
// R22 = R21 + gemm64 (out-proj) K-step 32->64: 2 independent K-sub-tiles per
//       barrier interval (barriers 32->16, MFMA/interval/wave 4->8, LDS
//       8->16 KB, residency unchanged at 4 blk/CU). Same lever that won
//       R16/R18 on attn; gemm64 had the worst MFMA-per-barrier ratio in the
//       pipeline (4 MFMA ~ 20 cyc per barrier). Bit-identical math.
// ---------------------------------------------------------------------------

#define B_   2
#define S_   2048
#define H_   1024
#define R_   16
#define BS_  (B_*S_)     // 4096 rows
#define NQKV 3072        // R*K*3
#define LOG2E 1.44269504088896f

typedef float    floatx4 __attribute__((ext_vector_type(4)));
typedef _Float16 half8   __attribute__((ext_vector_type(8)));
typedef _Float16 half4   __attribute__((ext_vector_type(4)));
typedef __fp16   fp16x2  __attribute__((ext_vector_type(2)));  // cvt_pkrtz ret

#if __has_builtin(__builtin_amdgcn_exp2f)
#define EXP2(x) __builtin_amdgcn_exp2f(x)
#else
#define EXP2(x) exp2f(x)
#endif

// async global -> LDS, 16 B per lane (lds dest = wave-uniform base + lane*16)
__device__ __forceinline__ void gl_lds16(const _Float16* g, _Float16* l) {
    __builtin_amdgcn_global_load_lds(
        (const __attribute__((address_space(1))) unsigned int*)g,
        (__attribute__((address_space(3))) unsigned int*)l, 16, 0, 0);
}

// ------- fused preprocessing: x cast + W_qkv^T + W_out^T (one launch) ------
// grid 8192: [0,4096) cast x; [4096,7168) W_qkv transpose; [7168,8192) W_out.
__global__ __launch_bounds__(256) void prep0_kernel(
    const float* __restrict__ x, _Float16* __restrict__ x_h,
    const float* __restrict__ W_qkv, _Float16* __restrict__ wqkv_t,
    const float* __restrict__ W_out, _Float16* __restrict__ wout_t)
{
    __shared__ float tile[32][33];
    int bid = blockIdx.x, tid = threadIdx.x;
    if (bid < 4096) {
        int i = bid * 1024 + tid * 4;
        float4 v = *(const float4*)(x + i);
        half4 h;
        h.x = (_Float16)v.x; h.y = (_Float16)v.y;
        h.z = (_Float16)v.z; h.w = (_Float16)v.w;
        *(half4*)(x_h + i) = h;
        return;
    }
    const float* in; _Float16* out; int rows, cols, bx, by;
    if (bid < 7168) {
        int t = bid - 4096;
        in = W_qkv; out = wqkv_t; rows = H_; cols = NQKV;
        bx = t % 96; by = t / 96;
    } else {
        int t = bid - 7168;
        in = W_out; out = wout_t; rows = H_; cols = H_;
        bx = t & 31; by = t >> 5;
    }
    int cx = bx * 32, ry = by * 32;
    int tx = tid & 31, ty = tid >> 5;   // ty 0..7
#pragma unroll
    for (int i = 0; i < 32; i += 8)
        tile[ty + i][tx] = in[(size_t)(ry + ty + i) * cols + cx + tx];
    __syncthreads();
#pragma unroll
    for (int i = 0; i < 32; i += 8)
        out[(size_t)(cx + ty + i) * rows + ry + tx] = (_Float16)tile[tx][ty + i];
}

// ---------- f16 MFMA GEMM 128x128, dbuf:  Ch(f16) = A @ Bt^T + bias --------
__global__ __launch_bounds__(256) void gemm_f16_mfma(
    const _Float16* __restrict__ A, const _Float16* __restrict__ Bt,
    const float* __restrict__ bias, _Float16* __restrict__ Ch,
    int M, int N, int Kd)
{
    __shared__ _Float16 Als[2][4096];
    __shared__ _Float16 Bls[2][4096];
    int tid  = threadIdx.x;
    int lane = tid & 63, w = tid >> 6;
    int wr = w >> 1, wc = w & 1;
    int fr = lane & 15, fq = lane >> 4;

    int nbx = gridDim.x;
    int orig = blockIdx.x + nbx * blockIdx.y;
    int nwg  = nbx * gridDim.y;
    int swz  = (nwg & 7) ? orig : ((orig & 7) * (nwg >> 3) + (orig >> 3));
    int bx = swz % nbx, by = swz / nbx;
    int m0 = by * 128, n0 = bx * 128;

    floatx4 acc[4][4] = {};

    const _Float16* ga[2]; const _Float16* gb[2];
    int loff[2];
#pragma unroll
    for (int i2 = 0; i2 < 2; ++i2) {
        int ch = 2 * w + i2;
        int row = ch * 16 + (lane >> 2), col = (lane & 3) * 8;
        ga[i2] = A  + (size_t)(m0 + row) * Kd + col;
        gb[i2] = Bt + (size_t)(n0 + row) * Kd + col;
        loff[i2] = ch * 512;
    }

    int nIter = Kd >> 5;
#pragma unroll
    for (int i2 = 0; i2 < 2; ++i2) {
        gl_lds16(ga[i2], &Als[0][loff[i2]]);
        gl_lds16(gb[i2], &Bls[0][loff[i2]]);
    }

    for (int it = 0; it < nIter; ++it) {
        int cur = it & 1;
        __syncthreads();               // buf[cur] staged; buf[cur^1] free
        if (it + 1 < nIter) {
            int k1 = (it + 1) << 5;
#pragma unroll
            for (int i2 = 0; i2 < 2; ++i2) {
                gl_lds16(ga[i2] + k1, &Als[cur ^ 1][loff[i2]]);
                gl_lds16(gb[i2] + k1, &Bls[cur ^ 1][loff[i2]]);
            }
        }
        const _Float16* Ab = Als[cur];
        const _Float16* Bb = Bls[cur];
        half8 af[4], bf[4];
#pragma unroll
        for (int i = 0; i < 4; ++i)
            af[i] = *(const half8*)(Ab + (wr * 64 + i * 16 + fr) * 32 + fq * 8);
#pragma unroll
        for (int j = 0; j < 4; ++j)
            bf[j] = *(const half8*)(Bb + (wc * 64 + j * 16 + fr) * 32 + fq * 8);
#pragma unroll
        for (int i = 0; i < 4; ++i)
#pragma unroll
            for (int j = 0; j < 4; ++j)
                acc[i][j] = __builtin_amdgcn_mfma_f32_16x16x32_f16(
                    af[i], bf[j], acc[i][j], 0, 0, 0);
    }

#pragma unroll
    for (int i = 0; i < 4; ++i)
#pragma unroll
        for (int j = 0; j < 4; ++j)
#pragma unroll
            for (int r2 = 0; r2 < 4; ++r2) {
                int row = m0 + wr * 64 + i * 16 + fq * 4 + r2;
                int col = n0 + wc * 64 + j * 16 + fr;
                Ch[(size_t)row * N + col] = (_Float16)(acc[i][j][r2] + bias[col]);
            }
}

// ---------- f16 MFMA GEMM 64x64, dbuf, BK=64: Cf = A@Bt^T + bias + resid ---
// 4 waves, each 32x32 (2x2 frags). grid (N/64, M/64) -> 4 blocks/CU.
// 2 independent K-sub-tiles (32 each) per barrier interval: barriers 32->16,
// 8 MFMA/wave/interval. LDS 16 KB (2 bufs x 2 sub-tiles x 2048 f16 per mat).
__global__ __launch_bounds__(256) void gemm64_f16_mfma(
    const _Float16* __restrict__ A, const _Float16* __restrict__ Bt,
    const float* __restrict__ bias, const float* __restrict__ resid,
    float* __restrict__ Cf, int M, int N, int Kd)
{
    __shared__ _Float16 Als[2][4096];
    __shared__ _Float16 Bls[2][4096];
    int tid = threadIdx.x, lane = tid & 63, w = tid >> 6;
    int wr = w >> 1, wc = w & 1;
    int fr = lane & 15, fq = lane >> 4;

    int nbx = gridDim.x;
    int orig = blockIdx.x + nbx * blockIdx.y;
    int nwg  = nbx * gridDim.y;
    int swz  = (nwg & 7) ? orig : ((orig & 7) * (nwg >> 3) + (orig >> 3));
    int bx = swz % nbx, by = swz / nbx;
    int m0 = by * 64, n0 = bx * 64;

    floatx4 acc[2][2] = {};

    // staging: wave w stages rows [w*16, w*16+16) of A and B for each of the
    // 2 K-sub-tiles: lane L -> row w*16+(L>>2), col (L&3)*8 within sub-tile.
    int srow = w * 16 + (lane >> 2), scol = (lane & 3) * 8;
    const _Float16* ga = A  + (size_t)(m0 + srow) * Kd + scol;
    const _Float16* gb = Bt + (size_t)(n0 + srow) * Kd + scol;
    int loff = w * 512;

    int nIter = Kd >> 6;               // 64 K per interval
#pragma unroll
    for (int s = 0; s < 2; ++s) {
        gl_lds16(ga + s * 32, &Als[0][s * 2048 + loff]);
        gl_lds16(gb + s * 32, &Bls[0][s * 2048 + loff]);
    }

    for (int it = 0; it < nIter; ++it) {
        int cur = it & 1;
        __syncthreads();               // buf[cur] staged; buf[cur^1] free
        if (it + 1 < nIter) {
            int k1 = (it + 1) << 6;
#pragma unroll
            for (int s = 0; s < 2; ++s) {
                gl_lds16(ga + k1 + s * 32, &Als[cur ^ 1][s * 2048 + loff]);
                gl_lds16(gb + k1 + s * 32, &Bls[cur ^ 1][s * 2048 + loff]);
            }
        }
#pragma unroll
        for (int s = 0; s < 2; ++s) {
            const _Float16* Ab = &Als[cur][s * 2048];
            const _Float16* Bb = &Bls[cur][s * 2048];
            half8 af[2], bf[2];
#pragma unroll
            for (int i = 0; i < 2; ++i)
                af[i] = *(const half8*)(Ab + (wr * 32 + i * 16 + fr) * 32 + fq * 8);
#pragma unroll
            for (int j = 0; j < 2; ++j)
                bf[j] = *(const half8*)(Bb + (wc * 32 + j * 16 + fr) * 32 + fq * 8);
#pragma unroll
            for (int i = 0; i < 2; ++i)
#pragma unroll
                for (int j = 0; j < 2; ++j)
                    acc[i][j] = __builtin_amdgcn_mfma_f32_16x16x32_f16(
                        af[i], bf[j], acc[i][j], 0, 0, 0);
        }
    }

#pragma unroll
    for (int i = 0; i < 2; ++i)
#pragma unroll
        for (int j = 0; j < 2; ++j)
#pragma unroll
            for (int r2 = 0; r2 < 4; ++r2) {
                int row = m0 + wr * 32 + i * 16 + fq * 4 + r2;
                int col = n0 + wc * 32 + j * 16 + fr;
                Cf[(size_t)row * N + col] =
                    acc[i][j][r2] + bias[col] + resid[(size_t)row * N + col];
            }
}

// ------- fused prep1 (VECTORIZED): k-norm + RoPE -> qt/kt; V -> vt2 image --
// grid (head 32, s-tile 32), block 256 = 4 waves. Lane decomposition for the
// vector path: lane = 8*r + b8 -> row r (of 8 per pass), d-block b8 (8 elems).
// k-norm: in-lane 8-sum + shfl_xor(1,2,4) across the row's 8 lanes.
// RoPE pair d <-> d^32 lives at lane^4 (same row, same norm).
__global__ __launch_bounds__(256) void prep1_kernel(
    const _Float16* __restrict__ qkvh, const float* __restrict__ pos,
    _Float16* __restrict__ qt, _Float16* __restrict__ kt,
    _Float16* __restrict__ vt2)
{
    __shared__ float tile[64][65];
    int head = blockIdx.x, tau = blockIdx.y;
    int s0 = tau * 64;
    int b = head >> 4, rh = head & 15;
    int lane = threadIdx.x & 63, w = threadIdx.x >> 6;
    int r = lane >> 3, b8 = lane & 7;

    // ---- Part A: V tile -> LDS (half8 loads; wave w owns rows [w*16,w*16+16))
#pragma unroll
    for (int p = 0; p < 2; ++p) {
        int si = w * 16 + p * 8 + r;
        half8 v8 = *(const half8*)(qkvh + (size_t)(b * S_ + s0 + si) * NQKV
                                   + rh * 192 + 128 + b8 * 8);
#pragma unroll
        for (int e = 0; e < 8; ++e)
            tile[si][b8 * 8 + e] = (float)v8[e];
    }
    __syncthreads();
    // ---- V image write (keymap + bank XOR baked), unchanged ----
    {
        int P = lane;
        int op = P >> 3;
        int hi = (P >> 2) & 1, lo = P & 3;
#pragma unroll
        for (int d = w; d < 64; d += 4) {
            int ol = op ^ (d & 7);
            int key = 32 * (ol >> 2) + 16 * hi + 4 * (ol & 3) + lo;
            vt2[(((size_t)head * 32 + tau) * 64 + d) * 64 + P] = (_Float16)tile[key][d];
        }
    }

    // ---- Part B: q/k k-norm + RoPE, half8 vector path ----
#pragma unroll
    for (int p = 0; p < 2; ++p) {
        int s = s0 + w * 16 + p * 8 + r;
        int bs = b * S_ + s;
        const _Float16* base = qkvh + (size_t)bs * NQKV + rh * 192 + b8 * 8;
        union { half8 v; int i[4]; } q8, k8, qp8, kp8;
        q8.v = *(const half8*)(base);
        k8.v = *(const half8*)(base + 64);

        // k row norm: 8 lanes (same r) hold the 64 k-values
        float ss = 0.f;
#pragma unroll
        for (int e = 0; e < 8; ++e) { float kv = (float)k8.v[e]; ss += kv * kv; }
        ss += __shfl_xor(ss, 1);
        ss += __shfl_xor(ss, 2);
        ss += __shfl_xor(ss, 4);
        float rinv = rsqrtf(ss);

        // RoPE partner block (d ^ 32) = lane ^ 4 (same row -> same rinv)
#pragma unroll
        for (int e2 = 0; e2 < 4; ++e2) {
            qp8.i[e2] = __shfl_xor(q8.i[e2], 4);
            kp8.i[e2] = __shfl_xor(k8.i[e2], 4);
        }

        const float* pp = pos + (size_t)bs * 64 + (b8 & 3) * 8;
        float4 sn0 = *(const float4*)(pp);
        float4 sn1 = *(const float4*)(pp + 4);
        float4 cs0 = *(const float4*)(pp + 32);
        float4 cs1 = *(const float4*)(pp + 36);
        float sn[8] = {sn0.x, sn0.y, sn0.z, sn0.w, sn1.x, sn1.y, sn1.z, sn1.w};
        float cs[8] = {cs0.x, cs0.y, cs0.z, cs0.w, cs1.x, cs1.y, cs1.z, cs1.w};

        bool lo = (b8 < 4);
        float qo[8], ko[8];
#pragma unroll
        for (int e = 0; e < 8; ++e) {
            float qv = (float)q8.v[e];
            float qp = (float)qp8.v[e];
            float kv = (float)k8.v[e] * rinv;
            float kp = (float)kp8.v[e] * rinv;
            if (lo) { qo[e] = qv * cs[e] - qp * sn[e];
                      ko[e] = kv * cs[e] - kp * sn[e]; }
            else    { qo[e] = qp * sn[e] + qv * cs[e];
                      ko[e] = kp * sn[e] + kv * cs[e]; }
        }

        union { half8 v; fp16x2 h2[4]; } qe, ke;
#pragma unroll
        for (int e2 = 0; e2 < 4; ++e2) {
            qe.h2[e2] = __builtin_amdgcn_cvt_pkrtz(qo[2 * e2] * LOG2E,
                                                   qo[2 * e2 + 1] * LOG2E);
            ke.h2[e2] = __builtin_amdgcn_cvt_pkrtz(ko[2 * e2], ko[2 * e2 + 1]);
        }
        size_t oidx = ((size_t)head * S_ + s) * 64 + b8 * 8;
        *(half8*)(qt + oidx) = qe.v;
        *(half8*)(kt + oidx) = ke.v;
    }
}

// ------- transposed MFMA flash attention, 8-wave blocks, KVBLK=256 ---------
// grid (8 q-tiles of 256, 32 heads) [qtile-fastest], block 512 = 8 waves;
// wave w owns 32 queries (2 q-groups of 16) at q0 + w*32. 8 intervals x 256
// keys (4 sub-tiles of 64) cover all 2048 keys. K/V double-buffered in LDS
// (128 KB); 8 waves share the tile. Static-max softmax; normalization in
// epilogue; writes ctx directly.
// XCD swizzle: chunk of 32 blocks = 4 heads x 8 qtiles -> 2 MB K/V per L2.
__global__ __launch_bounds__(512) void attn_mfma_kernel(
    const _Float16* __restrict__ qt, const _Float16* __restrict__ kt,
    const _Float16* __restrict__ vt2, _Float16* __restrict__ ctx)
{
    __shared__ _Float16 Kls[2][16384];
    __shared__ _Float16 Vls[2][16384];

    int orig = blockIdx.x + 8 * blockIdx.y;        // 256 blocks
    int swz  = (orig & 7) * 32 + (orig >> 3);
    int q0   = (swz & 7) * 256;
    int head = swz >> 3;

    int b = head >> 4, rh = head & 15;
    int tid = threadIdx.x, lane = tid & 63, w = tid >> 6;   // w in [0,8)
    int g = lane >> 4, c = lane & 15;

    // Q B-frags + static softmax bound mL = |q~| (log2 units) per q-group
    half8 qf[2][2];
    floatx4 mz[2];                  // broadcast(-mL) for MFMA C-init
    float l_s[2] = {0.f, 0.f};
#pragma unroll
    for (int qg = 0; qg < 2; ++qg) {
        const _Float16* qp =
            qt + ((size_t)head * S_ + q0 + w * 32 + qg * 16 + c) * 64 + 8 * g;
        qf[qg][0] = *(const half8*)qp;
        qf[qg][1] = *(const half8*)(qp + 32);
        float qq = 0.f;
#pragma unroll
        for (int i = 0; i < 8; ++i) {
            float a = (float)qf[qg][0][i], b2 = (float)qf[qg][1][i];
            qq += a * a + b2 * b2;
        }
        qq += __shfl_xor(qq, 16);
        qq += __shfl_xor(qq, 32);
        float nm = -sqrtf(qq);    // s_log2 <= |q~|*|k^| (k^ unit norm)
        mz[qg][0] = nm; mz[qg][1] = nm; mz[qg][2] = nm; mz[qg][3] = nm;
    }

    floatx4 o_acc[2][4] = {};

    // staging geometry: wave w stages K chunk w and V chunk w of each
    // sub-tile (chunk = 8 keys x 64 d = 512 f16, staged 16B/lane).
    int krow = w * 8 + (lane >> 3);
    int koct = (lane & 7) ^ (lane >> 3);
    const _Float16* kg = kt + ((size_t)head * S_ + krow) * 64 + koct * 8;
    const _Float16* vg = vt2 + ((size_t)head * 32) * 4096 + w * 512 + lane * 8;
    int loff = w * 512;

    int co = c & 7;        // XOR swizzle term for frag reads

    // prologue: stage sub-tiles 0..3 into buffer 0
#pragma unroll
    for (int s = 0; s < 4; ++s) {
        gl_lds16(kg + (size_t)s * 4096, &Kls[0][s * 4096 + loff]);
        gl_lds16(vg + (size_t)s * 4096, &Vls[0][s * 4096 + loff]);
    }

    for (int jt = 0; jt < 8; ++jt) {
        int cur = jt & 1;
        __syncthreads();       // buf[cur] staged (4 sub-tiles); buf[cur^1] free
        if (jt + 1 < 8) {
#pragma unroll
            for (int s = 0; s < 4; ++s) {
                size_t joff = (size_t)(4 * (jt + 1) + s) * 4096;
                gl_lds16(kg + joff, &Kls[cur ^ 1][s * 4096 + loff]);
                gl_lds16(vg + joff, &Vls[cur ^ 1][s * 4096 + loff]);
            }
        }

#pragma unroll
        for (int s = 0; s < 4; ++s) {
            const _Float16* Kbuf = &Kls[cur][s * 4096];
            const _Float16* Vbuf = &Vls[cur][s * 4096];

            // ---- K fragments once, shared by both q-groups ----
            half8 kfr[8];
#pragma unroll
            for (int t = 0; t < 4; ++t) {
                const _Float16* krw = Kbuf + (16 * t + c) * 64;
                kfr[2 * t]     = *(const half8*)(krw + ((g) ^ co) * 8);
                kfr[2 * t + 1] = *(const half8*)(krw + ((4 + g) ^ co) * 8);
            }

            union { half8 v; fp16x2 h2[4]; } pf[2][2];
#pragma unroll
            for (int qg = 0; qg < 2; ++qg) {
                floatx4 sacc[4];
#pragma unroll
                for (int t = 0; t < 4; ++t) {
                    floatx4 z = mz[qg];   // C-init = -mL : sacc = S - mL
                    z = __builtin_amdgcn_mfma_f32_16x16x32_f16(
                        kfr[2 * t], qf[qg][0], z, 0, 0, 0);
                    z = __builtin_amdgcn_mfma_f32_16x16x32_f16(
                        kfr[2 * t + 1], qf[qg][1], z, 0, 0, 0);
                    sacc[t] = z;
                }
                float ps = 0.f;
#pragma unroll
                for (int t = 0; t < 4; ++t)
#pragma unroll
                    for (int r = 0; r < 4; ++r) {
                        float p = EXP2(sacc[t][r]);
                        sacc[t][r] = p;
                        ps += p;
                    }
                l_s[qg] += ps;
                pf[qg][0].h2[0] = __builtin_amdgcn_cvt_pkrtz(sacc[0][0], sacc[0][1]);
                pf[qg][0].h2[1] = __builtin_amdgcn_cvt_pkrtz(sacc[0][2], sacc[0][3]);
                pf[qg][0].h2[2] = __builtin_amdgcn_cvt_pkrtz(sacc[1][0], sacc[1][1]);
                pf[qg][0].h2[3] = __builtin_amdgcn_cvt_pkrtz(sacc[1][2], sacc[1][3]);
                pf[qg][1].h2[0] = __builtin_amdgcn_cvt_pkrtz(sacc[2][0], sacc[2][1]);
                pf[qg][1].h2[1] = __builtin_amdgcn_cvt_pkrtz(sacc[2][2], sacc[2][3]);
                pf[qg][1].h2[2] = __builtin_amdgcn_cvt_pkrtz(sacc[3][0], sacc[3][1]);
                pf[qg][1].h2[3] = __builtin_amdgcn_cvt_pkrtz(sacc[3][2], sacc[3][3]);
            }

            // ---- V fragments once, shared; O^T += V^T @ P^T ----
#pragma unroll
            for (int t = 0; t < 4; ++t) {
                const _Float16* vrow = Vbuf + (16 * t + c) * 64;
                half8 v0 = *(const half8*)(vrow + ((g) ^ co) * 8);
                half8 v1 = *(const half8*)(vrow + ((4 + g) ^ co) * 8);
#pragma unroll
                for (int qg = 0; qg < 2; ++qg) {
                    o_acc[qg][t] = __builtin_amdgcn_mfma_f32_16x16x32_f16(
                        v0, pf[qg][0].v, o_acc[qg][t], 0, 0, 0);
                    o_acc[qg][t] = __builtin_amdgcn_mfma_f32_16x16x32_f16(
                        v1, pf[qg][1].v, o_acc[qg][t], 0, 0, 0);
                }
            }
        }
    }

    // ---- epilogue: normalize (f32) and write ctx directly ----
#pragma unroll
    for (int qg = 0; qg < 2; ++qg) {
        float lt = l_s[qg];
        lt += __shfl_xor(lt, 16);
        lt += __shfl_xor(lt, 32);
        float inv = 1.f / lt;
        int q = q0 + w * 32 + qg * 16 + c;
        size_t rowbase = (size_t)(b * S_ + q) * 1024 + rh * 64;
#pragma unroll
        for (int t = 0; t < 4; ++t) {
            union { half4 v; fp16x2 h2[2]; } e;
            e.h2[0] = __builtin_amdgcn_cvt_pkrtz(o_acc[qg][t][0] * inv,
                                                 o_acc[qg][t][1] * inv);
            e.h2[1] = __builtin_amdgcn_cvt_pkrtz(o_acc[qg][t][2] * inv,
                                                 o_acc[qg][t][3] * inv);
            *(half4*)(ctx + rowbase + 16 * t + 4 * g) = e.v;
        }
    }
}

// --------------------- LayerNorm in place on y[4096][1024] -----------------
__global__ __launch_bounds__(256) void ln_kernel(
    float* __restrict__ y, const float* __restrict__ g, const float* __restrict__ bb)
{
    int row = blockIdx.x, tid = threadIdx.x;
    float* p = y + (size_t)row * 1024;
    float4 v = ((const float4*)p)[tid];
    float sum = v.x + v.y + v.z + v.w;
    float sq  = v.x*v.x + v.y*v.y + v.z*v.z + v.w*v.w;
#pragma unroll
    for (int off = 32; off > 0; off >>= 1) {
        sum += __shfl_xor(sum, off);
        sq  += __shfl_xor(sq,  off);
    }
    __shared__ float rs[4], rq[4];
    int w = tid >> 6;
    if ((tid & 63) == 0) { rs[w] = sum; rq[w] = sq; }
    __syncthreads();
    sum = rs[0] + rs[1] + rs[2] + rs[3];
    sq  = rq[0] + rq[1] + rq[2] + rq[3];
    float mean = sum * (1.f / 1024.f);
    float var  = sq * (1.f / 1024.f) - mean * mean;
    float inv  = rsqrtf(var + 1e-5f);
    float4 gv = ((const float4*)g)[tid];
    float4 bv = ((const float4*)bb)[tid];
    v.x = (v.x - mean) * inv * gv.x + bv.x;
    v.y = (v.y - mean) * inv * gv.y + bv.y;
    v.z = (v.z - mean) * inv * gv.z + bv.z;
    v.w = (v.w - mean) * inv * gv.w + bv.w;
    ((float4*)p)[tid] = v;
}

// ---------------------------------------------------------------------------
extern "C" void kernel_launch(void* const* d_in, const int* in_sizes, int n_in,
                              void* d_out, int out_size, void* d_ws, size_t ws_size,
                              hipStream_t stream)
{
    const float* x     = (const float*)d_in[0];
    const float* pos   = (const float*)d_in[1];
    const float* W_qkv = (const float*)d_in[2];
    const float* b_qkv = (const float*)d_in[3];
    const float* W_out = (const float*)d_in[4];
    const float* b_out = (const float*)d_in[5];
    const float* ln_g  = (const float*)d_in[6];
    const float* ln_b  = (const float*)d_in[7];
    float* out = (float*)d_out;

    // workspace layout — 64 MB peak via time-disjoint aliasing:
    //   [ 0, 8)   x_h   (steps 1-2)   then ctx   (steps 4-6, attn writes it)
    //   [ 8,14)   wqkv_t (steps 1-2)
    //   [14,16)   wout_t (steps 1-6)
    //   [16,40)   qkvh  (steps 2-3)
    //   [40,48)   qt    (steps 3-4)
    //   [48,56)   kt    (steps 3-4)
    //   [56,64)   vt2   (steps 3-4)
    char* ws = (char*)d_ws;
    _Float16* x_h    = (_Float16*)(ws);
    _Float16* ctx_h  = (_Float16*)(ws);                       // alias x_h
    _Float16* wqkv_t = (_Float16*)(ws + ((size_t)8  << 20));
    _Float16* wout_t = (_Float16*)(ws + ((size_t)14 << 20));
    _Float16* qkvh   = (_Float16*)(ws + ((size_t)16 << 20));
    _Float16* qt_h   = (_Float16*)(ws + ((size_t)40 << 20));
    _Float16* kt_h   = (_Float16*)(ws + ((size_t)48 << 20));
    _Float16* vt2_h  = (_Float16*)(ws + ((size_t)56 << 20));

    // 1) fused cast + weight transposes
    prep0_kernel<<<8192, 256, 0, stream>>>(x, x_h, W_qkv, wqkv_t, W_out, wout_t);

    // 2) qkv (f16) = x @ W_qkv + b_qkv
    gemm_f16_mfma<<<dim3(NQKV / 128, BS_ / 128), 256, 0, stream>>>(
        x_h, wqkv_t, b_qkv, qkvh, BS_, NQKV, H_);

    // 3) fused k-norm + RoPE + V-image (vectorized)
    prep1_kernel<<<dim3(32, 32), 256, 0, stream>>>(qkvh, pos, qt_h, kt_h, vt2_h);

    // 4) MFMA flash attention (8-wave blocks, KVBLK=256) -> ctx f16
    attn_mfma_kernel<<<dim3(8, 32), 512, 0, stream>>>(
        qt_h, kt_h, vt2_h, ctx_h);

    // 5) out (fp32) = x + ctx @ W_out + b_out   (64x64 tiles, BK=64)
    gemm64_f16_mfma<<<dim3(H_ / 64, BS_ / 64), 256, 0, stream>>>(
        ctx_h, wout_t, b_out, x, out, BS_, H_, H_);

    // 6) LayerNorm in place
    ln_kernel<<<BS_, 256, 0, stream>>>(out, ln_g, ln_b);
}